// Round 2
// baseline (6744.109 us; speedup 1.0000x reference)
//
#include <hip/hip_runtime.h>
#include <stdint.h>

#define E_ 4
#define N_ 2048
#define D_ 512
#define H_ 8
#define DH_ 64
#define FF_ 2048
#define L_ 4
#define MM_ 4096
#define QC_ 1024   // cross-attn query chunk rows

typedef unsigned short u16;
typedef __attribute__((ext_vector_type(8))) short short8;
typedef __attribute__((ext_vector_type(8))) __bf16 bf16x8;
typedef __attribute__((ext_vector_type(4))) float f32x4;

__device__ __forceinline__ u16 f2bf(float f) {
  uint32_t u = __builtin_bit_cast(uint32_t, f);
  u = (u + 0x7fffu + ((u >> 16) & 1u)) >> 16;
  return (u16)u;
}
__device__ __forceinline__ float bf2f_(u16 h) {
  uint32_t u = ((uint32_t)h) << 16;
  return __builtin_bit_cast(float, u);
}

// ---------------------------------------------------------------------------
// GEMM: C[M,N] = epi(alpha * op(A) @ op(B)^T), bf16 in, f32 acc.
//   TA=0: A stored [M][K] (lda = row stride). TA=1: A stored [K][M].
//   TB=0: B stored [N][K].                    TB=1: B stored [K][N].
// flags: 1=CLIP 2=BIAS(col) 4=RELU 8=RESID f32 16=ACCUM(+C) 32=RESID bf16
// epilogue order: v=alpha*acc -> clip -> +bias -> relu -> +resid -> +Cold
// ---------------------------------------------------------------------------
template<int TA, int TB>
__global__ __launch_bounds__(256) void gemm_k(
    const u16* __restrict__ A, int lda,
    const u16* __restrict__ B, int ldb,
    float* __restrict__ C, int ldc,
    u16* __restrict__ Cb, int ldcb,
    const float* __restrict__ bias, const void* __restrict__ resid, int ldr,
    int K, float alpha, float clo, float chi, int flags)
{
  __shared__ u16 As[64][40];
  __shared__ u16 Bs[64][40];
  const int m0 = blockIdx.y << 6, n0 = blockIdx.x << 6;
  const int t = threadIdx.x;
  const int lane = t & 63;
  const int w = t >> 6;
  const int wr = (w >> 1) << 5, wc = (w & 1) << 5;
  const int srow = t >> 2, skb = (t & 3) << 3;     // non-transposed staging
  const int kr = t & 31, mc = (t >> 5) << 3;       // transposed staging
  const int fr = lane & 15, kk = (lane >> 4) << 3;

  f32x4 acc[2][2];
  #pragma unroll
  for (int i = 0; i < 2; i++)
    #pragma unroll
    for (int j = 0; j < 2; j++)
      #pragma unroll
      for (int r = 0; r < 4; r++) acc[i][j][r] = 0.0f;

  for (int k0 = 0; k0 < K; k0 += 32) {
    if constexpr (TA == 0) {
      *(short8*)&As[srow][skb] =
          *(const short8*)(A + (size_t)(m0 + srow) * lda + (k0 + skb));
    } else {
      short8 va = *(const short8*)(A + (size_t)(k0 + kr) * lda + (m0 + mc));
      #pragma unroll
      for (int j = 0; j < 8; j++) As[mc + j][kr] = (u16)va[j];
    }
    if constexpr (TB == 0) {
      *(short8*)&Bs[srow][skb] =
          *(const short8*)(B + (size_t)(n0 + srow) * ldb + (k0 + skb));
    } else {
      short8 vb = *(const short8*)(B + (size_t)(k0 + kr) * ldb + (n0 + mc));
      #pragma unroll
      for (int j = 0; j < 8; j++) Bs[mc + j][kr] = (u16)vb[j];
    }
    __syncthreads();
    bf16x8 a0 = __builtin_bit_cast(bf16x8, *(const short8*)&As[wr + fr][kk]);
    bf16x8 a1 = __builtin_bit_cast(bf16x8, *(const short8*)&As[wr + 16 + fr][kk]);
    bf16x8 b0 = __builtin_bit_cast(bf16x8, *(const short8*)&Bs[wc + fr][kk]);
    bf16x8 b1 = __builtin_bit_cast(bf16x8, *(const short8*)&Bs[wc + 16 + fr][kk]);
    acc[0][0] = __builtin_amdgcn_mfma_f32_16x16x32_bf16(a0, b0, acc[0][0], 0, 0, 0);
    acc[0][1] = __builtin_amdgcn_mfma_f32_16x16x32_bf16(a0, b1, acc[0][1], 0, 0, 0);
    acc[1][0] = __builtin_amdgcn_mfma_f32_16x16x32_bf16(a1, b0, acc[1][0], 0, 0, 0);
    acc[1][1] = __builtin_amdgcn_mfma_f32_16x16x32_bf16(a1, b1, acc[1][1], 0, 0, 0);
    __syncthreads();
  }

  #pragma unroll
  for (int i = 0; i < 2; i++)
    #pragma unroll
    for (int j = 0; j < 2; j++) {
      const int row_b = m0 + wr + i * 16 + ((lane >> 4) << 2);
      const int col = n0 + wc + j * 16 + fr;
      #pragma unroll
      for (int r = 0; r < 4; r++) {
        const int row = row_b + r;
        float v = alpha * acc[i][j][r];
        if (flags & 1)  v = fminf(fmaxf(v, clo), chi);
        if (flags & 2)  v += bias[col];
        if (flags & 4)  v = fmaxf(v, 0.0f);
        if (flags & 8)  v += ((const float*)resid)[(size_t)row * ldr + col];
        if (flags & 32) v += bf2f_(((const u16*)resid)[(size_t)row * ldr + col]);
        if (flags & 16) v += C[(size_t)row * ldc + col];
        if (C)  C[(size_t)row * ldc + col] = v;
        if (Cb) Cb[(size_t)row * ldcb + col] = f2bf(v);
      }
    }
}

// ---------------------------------------------------------------------------
// Row softmax, len = NPER*256, f32 in -> bf16 out. May alias input when the
// output BYTE stride equals the input byte stride (each row rewrites itself).
// ---------------------------------------------------------------------------
template<int NPER>
__global__ __launch_bounds__(256) void softmax_rows(
    const float* __restrict__ in, long ld_in, u16* __restrict__ out, long ld_out)
{
  const size_t row = blockIdx.x;
  const float* x = in + row * ld_in;
  u16* o = out + row * ld_out;
  const int t = threadIdx.x;
  float v[NPER];
  float mx = -1e30f;
  #pragma unroll
  for (int i = 0; i < NPER; i++) { v[i] = x[t + i * 256]; mx = fmaxf(mx, v[i]); }
  __shared__ float r1[4], r2[4];
  #pragma unroll
  for (int d = 32; d > 0; d >>= 1) mx = fmaxf(mx, __shfl_down(mx, d));
  if ((t & 63) == 0) r1[t >> 6] = mx;
  __syncthreads();
  mx = fmaxf(fmaxf(r1[0], r1[1]), fmaxf(r1[2], r1[3]));
  float s = 0.0f;
  #pragma unroll
  for (int i = 0; i < NPER; i++) { v[i] = __expf(v[i] - mx); s += v[i]; }
  #pragma unroll
  for (int d = 32; d > 0; d >>= 1) s += __shfl_down(s, d);
  if ((t & 63) == 0) r2[t >> 6] = s;
  __syncthreads();
  const float inv = 1.0f / (r2[0] + r2[1] + r2[2] + r2[3]);
  #pragma unroll
  for (int i = 0; i < NPER; i++) o[t + i * 256] = f2bf(v[i] * inv);
}

// ---------------------------------------------------------------------------
// LayerNorm over D=512 per row; outputs nullable.
// ---------------------------------------------------------------------------
__global__ __launch_bounds__(256) void ln_plain_kernel(
    const float* __restrict__ in, float* __restrict__ outf, u16* __restrict__ outb)
{
  const size_t row = blockIdx.x;
  const float* x = in + row * D_;
  const int t = threadIdx.x;
  float a = x[t], b = x[t + 256];
  float s = a + b, ss = a * a + b * b;
  __shared__ float r1[4], r2[4];
  #pragma unroll
  for (int d = 32; d > 0; d >>= 1) { s += __shfl_down(s, d); ss += __shfl_down(ss, d); }
  if ((t & 63) == 0) { r1[t >> 6] = s; r2[t >> 6] = ss; }
  __syncthreads();
  s = r1[0] + r1[1] + r1[2] + r1[3];
  ss = r2[0] + r2[1] + r2[2] + r2[3];
  const float mu = s * (1.0f / D_);
  const float inv = rsqrtf(ss * (1.0f / D_) - mu * mu + 1e-5f);
  const float y0 = (a - mu) * inv, y1 = (b - mu) * inv;
  if (outf) { outf[row * D_ + t] = y0;       outf[row * D_ + t + 256] = y1; }
  if (outb) { outb[row * D_ + t] = f2bf(y0); outb[row * D_ + t + 256] = f2bf(y1); }
}

__global__ __launch_bounds__(256) void ln_affine_kernel(
    const float* __restrict__ in, const float* __restrict__ w, const float* __restrict__ b,
    float* __restrict__ outf, u16* __restrict__ outb)
{
  const size_t row = blockIdx.x;
  const float* x = in + row * D_;
  const int t = threadIdx.x;
  float a = x[t], c = x[t + 256];
  float s = a + c, ss = a * a + c * c;
  __shared__ float r1[4], r2[4];
  #pragma unroll
  for (int d = 32; d > 0; d >>= 1) { s += __shfl_down(s, d); ss += __shfl_down(ss, d); }
  if ((t & 63) == 0) { r1[t >> 6] = s; r2[t >> 6] = ss; }
  __syncthreads();
  s = r1[0] + r1[1] + r1[2] + r1[3];
  ss = r2[0] + r2[1] + r2[2] + r2[3];
  const float mu = s * (1.0f / D_);
  const float inv = rsqrtf(ss * (1.0f / D_) - mu * mu + 1e-5f);
  const float y0 = (a - mu) * inv * w[t] + b[t];
  const float y1 = (c - mu) * inv * w[t + 256] + b[t + 256];
  outf[row * D_ + t] = y0;       outf[row * D_ + t + 256] = y1;
  outb[row * D_ + t] = f2bf(y0); outb[row * D_ + t + 256] = f2bf(y1);
}

__global__ __launch_bounds__(256) void cvt_f2bf(
    const float* __restrict__ in, u16* __restrict__ out, size_t n)
{
  size_t i = (size_t)blockIdx.x * 256 + threadIdx.x;
  const size_t stride = (size_t)gridDim.x * 256;
  for (; i < n; i += stride) out[i] = f2bf(in[i]);
}

// io holds sum_e clip(upd_e); in-place: io = 0.9*mem + clamp(0.1*io, +-0.1)
__global__ __launch_bounds__(256) void memfinal_kernel(
    const float* __restrict__ mem, float* __restrict__ io)
{
  const size_t i = (size_t)blockIdx.x * 256 + threadIdx.x;
  const size_t n4 = (size_t)L_ * MM_ * D_ / 4;
  if (i >= n4) return;
  const f32x4 m = ((const f32x4*)mem)[i];
  const f32x4 u = ((f32x4*)io)[i];
  f32x4 r;
  #pragma unroll
  for (int k = 0; k < 4; k++)
    r[k] = 0.9f * m[k] + fminf(fmaxf(0.1f * u[k], -0.1f), 0.1f);
  ((f32x4*)io)[i] = r;
}

// pooled[e][d] += partial sums; grid (E, D/256, N/256); outs is bf16
__global__ __launch_bounds__(256) void pooled_reduce_kernel(
    const u16* __restrict__ outs, float* __restrict__ pooled)
{
  const int e = blockIdx.x, dc = blockIdx.y, nc = blockIdx.z;
  const int d = dc * 256 + threadIdx.x;
  const u16* p = outs + ((size_t)e * N_ + nc * 256) * D_ + d;
  float s = 0.0f;
  for (int i = 0; i < 256; i++) s += bf2f_(p[(size_t)i * D_]);
  atomicAdd(&pooled[e * D_ + d], s);
}

__global__ __launch_bounds__(256) void gate_kernel(
    const float* __restrict__ pooled, const float* __restrict__ gate,
    float* __restrict__ out_gw, float* __restrict__ ws_gw)
{
  const int t = threadIdx.x;
  const float g0 = gate[t], g1 = gate[t + 256];
  __shared__ float red[4][4];
  for (int e = 0; e < 4; e++) {
    float v = pooled[e * D_ + t] * g0 + pooled[e * D_ + t + 256] * g1;
    #pragma unroll
    for (int d = 32; d > 0; d >>= 1) v += __shfl_down(v, d);
    if ((t & 63) == 0) red[e][t >> 6] = v;
  }
  __syncthreads();
  if (t == 0) {
    float l[4], mx = -1e30f, sm = 0.0f;
    for (int e = 0; e < 4; e++) {
      l[e] = (red[e][0] + red[e][1] + red[e][2] + red[e][3]) * (1.0f / N_);
      l[e] = fminf(fmaxf(l[e], -10.0f), 10.0f);
      mx = fmaxf(mx, l[e]);
    }
    for (int e = 0; e < 4; e++) { l[e] = __expf(l[e] - mx); sm += l[e]; }
    for (int e = 0; e < 4; e++) { const float wv = l[e] / sm; out_gw[e] = wv; ws_gw[e] = wv; }
  }
}

// fused[n,d] = sum_e gw[e] * outs_bf[e,n,d]; grid 512 x 256, 8 elems/thread
__global__ __launch_bounds__(256) void fused_kernel(
    const u16* __restrict__ outs, const float* __restrict__ gw, float* __restrict__ out)
{
  const size_t i8 = ((size_t)blockIdx.x * 256 + threadIdx.x) * 8;
  const size_t s = (size_t)N_ * D_;
  if (i8 >= s) return;
  const float w0 = gw[0], w1 = gw[1], w2 = gw[2], w3 = gw[3];
  short8 v0 = *(const short8*)&outs[i8];
  short8 v1 = *(const short8*)&outs[i8 + s];
  short8 v2 = *(const short8*)&outs[i8 + 2 * s];
  short8 v3 = *(const short8*)&outs[i8 + 3 * s];
  float r[8];
  #pragma unroll
  for (int j = 0; j < 8; j++)
    r[j] = w0 * bf2f_((u16)v0[j]) + w1 * bf2f_((u16)v1[j]) +
           w2 * bf2f_((u16)v2[j]) + w3 * bf2f_((u16)v3[j]);
  *(f32x4*)&out[i8]     = *(f32x4*)&r[0];
  *(f32x4*)&out[i8 + 4] = *(f32x4*)&r[4];
}

// ---------------------------------------------------------------------------
extern "C" void kernel_launch(void* const* d_in, const int* in_sizes, int n_in,
                              void* d_out, int out_size, void* d_ws, size_t ws_size,
                              hipStream_t stream)
{
  (void)in_sizes; (void)n_in; (void)out_size; (void)ws_size;
  const float* tokens   = (const float*)d_in[0];
  const float* memories = (const float*)d_in[1];
  const float* ipw      = (const float*)d_in[2];
  const float* ipb      = (const float*)d_in[3];
  const float* opw      = (const float*)d_in[4];
  const float* opb      = (const float*)d_in[5];
  const float* w1       = (const float*)d_in[6];
  const float* b1       = (const float*)d_in[7];
  const float* w2       = (const float*)d_in[8];
  const float* b2       = (const float*)d_in[9];
  const float* n1w      = (const float*)d_in[10];
  const float* n1b      = (const float*)d_in[11];
  const float* n2w      = (const float*)d_in[12];
  const float* n2b      = (const float*)d_in[13];
  const float* aggw     = (const float*)d_in[14];
  const float* aggb     = (const float*)d_in[15];
  const float* ggate    = (const float*)d_in[16];

  float* out_fused = (float*)d_out;
  float* out_gate  = out_fused + (size_t)N_ * D_;
  float* out_mem   = out_gate + E_;          // [L][M][D], also the upd accumulator

  char* base = (char*)d_ws;
  size_t off = 0;
  auto alloc = [&](size_t b) -> char* {
    char* r = base + off; off += (b + 255) & ~(size_t)255; return r;
  };

  // total ~122 MiB
  u16* xln_bf  = (u16*)alloc((size_t)E_ * N_ * D_ * 2);
  u16* mem_bf  = (u16*)alloc((size_t)L_ * MM_ * D_ * 2);
  u16* ipw_bf  = (u16*)alloc((size_t)E_ * 3 * D_ * D_ * 2);
  u16* opw_bf  = (u16*)alloc((size_t)E_ * D_ * D_ * 2);
  u16* w1_bf   = (u16*)alloc((size_t)E_ * FF_ * D_ * 2);
  u16* w2_bf   = (u16*)alloc((size_t)E_ * D_ * FF_ * 2);
  u16* agg_bf  = (u16*)alloc((size_t)D_ * L_ * D_ * 2);
  u16* outs_bf = (u16*)alloc((size_t)E_ * N_ * D_ * 2);
  float* pooled = (float*)alloc((size_t)E_ * D_ * 4);
  float* gatew  = (float*)alloc(256);
  // scratch union (33.5 MiB): cross chunk scores [QC][3N] f32 (25.2M) |
  //   self scores [N][N] f32 (16.8M) | mem logits [N][M] f32 (full 33.5M)
  // pre/x2 overlaid in the tail (dead before the mem phase).
  char* scratch = alloc((size_t)N_ * MM_ * 4);
  float* scoresC = (float*)scratch;
  float* sscores = (float*)scratch;
  float* ml      = (float*)scratch;
  float* pre     = (float*)(scratch + 24u * 1024 * 1024);   // 4 MiB
  float* x2      = (float*)(scratch + 28u * 1024 * 1024);   // 4 MiB
  float* x0f   = (float*)alloc((size_t)N_ * D_ * 4);
  float* x1    = (float*)alloc((size_t)N_ * D_ * 4);
  u16* x1_bf   = (u16*)alloc((size_t)N_ * D_ * 2);
  u16* qkv_bf  = (u16*)alloc((size_t)N_ * 3 * D_ * 2);
  u16* sa_bf   = (u16*)alloc((size_t)N_ * D_ * 2);
  u16* x2_bf   = (u16*)alloc((size_t)N_ * D_ * 2);
  u16* ff1_bf  = (u16*)alloc((size_t)N_ * FF_ * 2);
  u16* retr_bf = ff1_bf;                                    // phase-disjoint union
  float* x3    = (float*)alloc((size_t)N_ * D_ * 4);
  u16* x3_bf   = (u16*)alloc((size_t)N_ * D_ * 2);

  auto G = [&](int ta, int tb,
               const u16* A, int lda, const u16* B, int ldb,
               float* C, int ldc, u16* Cb, int ldcb,
               const float* bias, const void* resid, int ldr,
               int M, int Nn, int K, float alpha, float clo, float chi, int flags) {
    dim3 g(Nn / 64, M / 64, 1);
    if (ta == 0 && tb == 0)
      gemm_k<0,0><<<g, 256, 0, stream>>>(A, lda, B, ldb, C, ldc, Cb, ldcb,
                                         bias, resid, ldr, K, alpha, clo, chi, flags);
    else if (ta == 0 && tb == 1)
      gemm_k<0,1><<<g, 256, 0, stream>>>(A, lda, B, ldb, C, ldc, Cb, ldcb,
                                         bias, resid, ldr, K, alpha, clo, chi, flags);
    else
      gemm_k<1,1><<<g, 256, 0, stream>>>(A, lda, B, ldb, C, ldc, Cb, ldcb,
                                         bias, resid, ldr, K, alpha, clo, chi, flags);
  };

  const float inv_sqrt_d = 0.04419417382415922f;  // 1/sqrt(512)

  hipMemsetAsync(out_mem, 0, (size_t)L_ * MM_ * D_ * 4, stream);
  hipMemsetAsync(pooled, 0, (size_t)E_ * D_ * 4, stream);

  ln_plain_kernel<<<E_ * N_, 256, 0, stream>>>(tokens, nullptr, xln_bf);
  cvt_f2bf<<<2048, 256, 0, stream>>>(memories, mem_bf, (size_t)L_ * MM_ * D_);
  cvt_f2bf<<<2048, 256, 0, stream>>>(ipw, ipw_bf, (size_t)E_ * 3 * D_ * D_);
  cvt_f2bf<<<1024, 256, 0, stream>>>(opw, opw_bf, (size_t)E_ * D_ * D_);
  cvt_f2bf<<<2048, 256, 0, stream>>>(w1, w1_bf, (size_t)E_ * FF_ * D_);
  cvt_f2bf<<<2048, 256, 0, stream>>>(w2, w2_bf, (size_t)E_ * D_ * FF_);
  cvt_f2bf<<<1024, 256, 0, stream>>>(aggw, agg_bf, (size_t)D_ * L_ * D_);

  for (int e = 0; e < E_; e++) {
    int js[3], c = 0;
    for (int j = 0; j < E_; j++) if (j != e) js[c++] = j;

    // f32 LN of this expert's tokens (residual precision)
    ln_plain_kernel<<<N_, 256, 0, stream>>>(tokens + (size_t)e * N_ * D_, x0f, nullptr);

    // ---- cross-expert attention (2 query chunks) ----
    for (int cc = 0; cc < 2; cc++) {
      const int q0 = cc * QC_;
      const u16* xq = xln_bf + ((size_t)e * N_ + q0) * D_;
      for (int s = 0; s < 3; s++)
        G(0, 0, xq, D_, xln_bf + (size_t)js[s] * N_ * D_, D_,
          scoresC + s * N_, 3 * N_, nullptr, 0, nullptr, nullptr, 0,
          QC_, N_, D_, inv_sqrt_d, -10.0f, 10.0f, 1);
      softmax_rows<24><<<QC_, 256, 0, stream>>>(scoresC, 3 * N_, (u16*)scoresC, 2L * 3 * N_);
      for (int s = 0; s < 3; s++)
        G(0, 1, (const u16*)scoresC + s * N_, 2 * 3 * N_,
          xln_bf + (size_t)js[s] * N_ * D_, D_,
          x1 + (size_t)q0 * D_, D_, (s == 2) ? x1_bf + (size_t)q0 * D_ : nullptr, D_,
          nullptr, (s == 0) ? (const void*)(x0f + (size_t)q0 * D_) : nullptr, D_,
          QC_, D_, N_, 1.0f, 0, 0, (s == 0) ? 8 : 16);
    }

    // ---- encoder layer ----
    G(0, 0, x1_bf, D_, ipw_bf + (size_t)e * 3 * D_ * D_, D_,
      nullptr, 0, qkv_bf, 3 * D_, ipb + (size_t)e * 3 * D_, nullptr, 0,
      N_, 3 * D_, D_, 1.0f, 0, 0, 2);
    for (int h = 0; h < H_; h++) {
      G(0, 0, qkv_bf + h * DH_, 3 * D_, qkv_bf + D_ + h * DH_, 3 * D_,
        sscores, N_, nullptr, 0, nullptr, nullptr, 0,
        N_, N_, DH_, 0.125f, 0, 0, 0);
      softmax_rows<8><<<N_, 256, 0, stream>>>(sscores, N_, (u16*)sscores, 2L * N_);
      G(0, 1, (const u16*)sscores, 2 * N_, qkv_bf + 2 * D_ + h * DH_, 3 * D_,
        nullptr, 0, sa_bf + h * DH_, D_, nullptr, nullptr, 0,
        N_, DH_, N_, 1.0f, 0, 0, 0);
    }
    G(0, 0, sa_bf, D_, opw_bf + (size_t)e * D_ * D_, D_,
      pre, D_, nullptr, 0, opb + (size_t)e * D_, x1, D_,
      N_, D_, D_, 1.0f, 0, 0, 2 | 8);
    ln_affine_kernel<<<N_, 256, 0, stream>>>(pre, n1w + (size_t)e * D_, n1b + (size_t)e * D_, x2, x2_bf);
    G(0, 0, x2_bf, D_, w1_bf + (size_t)e * FF_ * D_, D_,
      nullptr, 0, ff1_bf, FF_, b1 + (size_t)e * FF_, nullptr, 0,
      N_, FF_, D_, 1.0f, 0, 0, 2 | 4);
    G(0, 0, ff1_bf, FF_, w2_bf + (size_t)e * D_ * FF_, FF_,
      pre, D_, nullptr, 0, b2 + (size_t)e * D_, x2, D_,
      N_, D_, FF_, 1.0f, 0, 0, 2 | 8);
    ln_affine_kernel<<<N_, 256, 0, stream>>>(pre, n2w + (size_t)e * D_, n2b + (size_t)e * D_, x3, x3_bf);

    // ---- hierarchical memory ----
    for (int l = 0; l < L_; l++) {
      G(0, 0, x3_bf, D_, mem_bf + (size_t)l * MM_ * D_, D_,
        ml, MM_, nullptr, 0, nullptr, nullptr, 0,
        N_, MM_, D_, inv_sqrt_d, -10.0f, 10.0f, 1);
      softmax_rows<16><<<N_, 256, 0, stream>>>(ml, MM_, (u16*)ml, 2L * MM_);
      G(0, 1, (const u16*)ml, 2 * MM_, mem_bf + (size_t)l * MM_ * D_, D_,
        nullptr, 0, retr_bf + l * D_, L_ * D_, nullptr, nullptr, 0,
        N_, D_, MM_, 1.0f, 0, 0, 0);
      G(1, 1, (const u16*)ml, 2 * MM_, x3_bf, D_,
        out_mem + (size_t)l * MM_ * D_, D_, nullptr, 0, nullptr, nullptr, 0,
        MM_, D_, N_, 1.0f, -1.0f, 1.0f, 1 | 16);
    }
    G(0, 0, retr_bf, L_ * D_, agg_bf, L_ * D_,
      nullptr, 0, outs_bf + (size_t)e * N_ * D_, D_, aggb, x3, D_,
      N_, D_, L_ * D_, 1.0f, 0, 0, 2 | 8);
  }

  // ---- memory EMA + global fusion ----
  memfinal_kernel<<<(L_ * MM_ * D_ / 4 + 255) / 256, 256, 0, stream>>>(memories, out_mem);
  pooled_reduce_kernel<<<dim3(E_, D_ / 256, N_ / 256), 256, 0, stream>>>(outs_bf, pooled);
  gate_kernel<<<1, 256, 0, stream>>>(pooled, ggate, out_gate, gatew);
  fused_kernel<<<512, 256, 0, stream>>>(outs_bf, gatew, out_fused);
}

// Round 3
// 6226.280 us; speedup vs baseline: 1.0832x; 1.0832x over previous
//
#include <hip/hip_runtime.h>
#include <stdint.h>

#define E_ 4
#define N_ 2048
#define D_ 512
#define H_ 8
#define DH_ 64
#define FF_ 2048
#define L_ 4
#define MM_ 4096
#define QC_ 1024   // cross-attn query chunk rows

typedef unsigned short u16;
typedef __attribute__((ext_vector_type(8))) short short8;
typedef __attribute__((ext_vector_type(8))) __bf16 bf16x8;
typedef __attribute__((ext_vector_type(4))) float f32x4;

__device__ __forceinline__ u16 f2bf(float f) {
  uint32_t u = __builtin_bit_cast(uint32_t, f);
  u = (u + 0x7fffu + ((u >> 16) & 1u)) >> 16;
  return (u16)u;
}
__device__ __forceinline__ float bf2f_(u16 h) {
  uint32_t u = ((uint32_t)h) << 16;
  return __builtin_bit_cast(float, u);
}

typedef __attribute__((address_space(3))) char lds_char;
typedef __attribute__((address_space(1))) const char glb_char;
__device__ __forceinline__ void glds16(const void* g, void* l) {
  __builtin_amdgcn_global_load_lds((glb_char*)g, (lds_char*)l, 16, 0, 0);
}

// ---------------------------------------------------------------------------
// flags: 1=CLIP 2=BIAS(col) 4=RELU 8=RESID f32 16=ACCUM(+C) 32=RESID bf16
//        64=ATOMIC-ADD into C (f32), exclusive with stores
// epilogue order: v=alpha*acc -> clip -> +bias -> relu -> +resid -> +Cold
// z offsets: A += (z/zdiv)*sAz1 + (z%zdiv)*sAz2 (same for B); C/Cb += z*sCz.
// ---------------------------------------------------------------------------

// ============ 128 x BN tile, NT only, global_load_lds staging ============
template<int BN>
__global__ __launch_bounds__(256) void gemm_big(
    const u16* __restrict__ A, int lda, long sAz1, long sAz2,
    const u16* __restrict__ B, int ldb, long sBz1, long sBz2,
    float* __restrict__ C, int ldc, long sCz,
    u16* __restrict__ Cb, int ldcb, long sCbz,
    const float* __restrict__ bias, const void* __restrict__ resid, int ldr,
    int K, int zdiv, float alpha, float clo, float chi, int flags)
{
  __shared__ u16 As[128 * 32];
  __shared__ u16 Bs[BN * 32];
  const int z = blockIdx.z;
  A += (size_t)(z / zdiv) * sAz1 + (size_t)(z % zdiv) * sAz2;
  B += (size_t)(z / zdiv) * sBz1 + (size_t)(z % zdiv) * sBz2;
  const int m0 = blockIdx.y * 128, n0 = blockIdx.x * BN;
  const int t = threadIdx.x, lane = t & 63, w = t >> 6;
  constexpr int NI = (BN == 128) ? 4 : 2;
  const int WR = (BN == 128) ? ((w >> 1) * 64) : (w * 32);
  const int WC = (BN == 128) ? ((w & 1) * 64) : 0;
  const int fr = lane & 15, kg = lane >> 4;
  const int srw = lane >> 2, sck = (lane & 3) << 3;

  const u16* gA0 = A + (size_t)(m0 + w * 16 + srw) * lda + sck;
  const u16* gA1 = A + (size_t)(m0 + 64 + w * 16 + srw) * lda + sck;
  const u16* gB0 = B + (size_t)(n0 + w * 16 + srw) * ldb + sck;
  const u16* gB1 = nullptr;
  if constexpr (BN == 128) gB1 = B + (size_t)(n0 + 64 + w * 16 + srw) * ldb + sck;
  u16* lA0 = &As[(w * 16) * 32];
  u16* lA1 = &As[(64 + w * 16) * 32];
  u16* lB0 = &Bs[(w * 16) * 32];
  u16* lB1 = nullptr;
  if constexpr (BN == 128) lB1 = &Bs[(64 + w * 16) * 32];

  f32x4 acc[NI][4];
  #pragma unroll
  for (int i = 0; i < NI; i++)
    #pragma unroll
    for (int j = 0; j < 4; j++)
      #pragma unroll
      for (int r = 0; r < 4; r++) acc[i][j][r] = 0.0f;

  for (int k0 = 0; k0 < K; k0 += 32) {
    glds16(gA0, lA0); glds16(gA1, lA1); glds16(gB0, lB0);
    if constexpr (BN == 128) glds16(gB1, lB1);
    gA0 += 32; gA1 += 32; gB0 += 32;
    if constexpr (BN == 128) gB1 += 32;
    __syncthreads();
    bf16x8 af[NI], bfr[4];
    #pragma unroll
    for (int i = 0; i < NI; i++)
      af[i] = __builtin_bit_cast(bf16x8, *(const short8*)&As[(WR + i * 16 + fr) * 32 + kg * 8]);
    #pragma unroll
    for (int j = 0; j < 4; j++)
      bfr[j] = __builtin_bit_cast(bf16x8, *(const short8*)&Bs[(WC + j * 16 + fr) * 32 + kg * 8]);
    #pragma unroll
    for (int i = 0; i < NI; i++)
      #pragma unroll
      for (int j = 0; j < 4; j++)
        acc[i][j] = __builtin_amdgcn_mfma_f32_16x16x32_bf16(af[i], bfr[j], acc[i][j], 0, 0, 0);
    __syncthreads();
  }

  if (C)  C  += (size_t)z * sCz;
  if (Cb) Cb += (size_t)z * sCbz;
  #pragma unroll
  for (int i = 0; i < NI; i++)
    #pragma unroll
    for (int j = 0; j < 4; j++) {
      const int row_b = m0 + WR + i * 16 + kg * 4;
      const int col = n0 + WC + j * 16 + fr;
      #pragma unroll
      for (int r = 0; r < 4; r++) {
        const int row = row_b + r;
        float v = alpha * acc[i][j][r];
        if (flags & 1)  v = fminf(fmaxf(v, clo), chi);
        if (flags & 2)  v += bias[col];
        if (flags & 4)  v = fmaxf(v, 0.0f);
        if (flags & 8)  v += ((const float*)resid)[(size_t)row * ldr + col];
        if (flags & 32) v += bf2f_(((const u16*)resid)[(size_t)row * ldr + col]);
        if (flags & 64) { atomicAdd(&C[(size_t)row * ldc + col], v); continue; }
        if (flags & 16) v += C[(size_t)row * ldc + col];
        if (C)  C[(size_t)row * ldc + col] = v;
        if (Cb) Cb[(size_t)row * ldcb + col] = f2bf(v);
      }
    }
}

// ============ 64x64 tile; TA/TB=1 means operand stored [K][rows] ============
template<int TA, int TB>
__global__ __launch_bounds__(256) void gemm_k(
    const u16* __restrict__ A, int lda, long sAz1, long sAz2,
    const u16* __restrict__ B, int ldb, long sBz1, long sBz2,
    float* __restrict__ C, int ldc, long sCz,
    u16* __restrict__ Cb, int ldcb, long sCbz,
    const float* __restrict__ bias, const void* __restrict__ resid, int ldr,
    int K, int zdiv, float alpha, float clo, float chi, int flags)
{
  __shared__ u16 As[64 * 32];
  __shared__ u16 Bs[64 * 32];
  const int z = blockIdx.z;
  A += (size_t)(z / zdiv) * sAz1 + (size_t)(z % zdiv) * sAz2;
  B += (size_t)(z / zdiv) * sBz1 + (size_t)(z % zdiv) * sBz2;
  const int m0 = blockIdx.y << 6, n0 = blockIdx.x << 6;
  const int t = threadIdx.x, lane = t & 63, w = t >> 6;
  const int wr = (w >> 1) << 5, wc = (w & 1) << 5;
  const int fr = lane & 15, kg = lane >> 4;
  const int srw = lane >> 2, sck = (lane & 3) << 3;
  const int kr = t & 31, mc = (t >> 5) << 3;

  const u16 *gA, *gB;
  if constexpr (TA == 0) gA = A + (size_t)(m0 + w * 16 + srw) * lda + sck;
  else                   gA = A + (size_t)kr * lda + m0 + mc;
  if constexpr (TB == 0) gB = B + (size_t)(n0 + w * 16 + srw) * ldb + sck;
  else                   gB = B + (size_t)kr * ldb + n0 + mc;

  f32x4 acc[2][2];
  #pragma unroll
  for (int i = 0; i < 2; i++)
    #pragma unroll
    for (int j = 0; j < 2; j++)
      #pragma unroll
      for (int r = 0; r < 4; r++) acc[i][j][r] = 0.0f;

  for (int k0 = 0; k0 < K; k0 += 32) {
    if constexpr (TA == 0) {
      glds16(gA, &As[(w * 16) * 32]); gA += 32;
    } else {
      short8 va = *(const short8*)gA; gA += (size_t)32 * lda;
      #pragma unroll
      for (int j = 0; j < 8; j++) As[(mc + j) * 32 + kr] = (u16)va[j];
    }
    if constexpr (TB == 0) {
      glds16(gB, &Bs[(w * 16) * 32]); gB += 32;
    } else {
      short8 vb = *(const short8*)gB; gB += (size_t)32 * ldb;
      #pragma unroll
      for (int j = 0; j < 8; j++) Bs[(mc + j) * 32 + kr] = (u16)vb[j];
    }
    __syncthreads();
    bf16x8 a0 = __builtin_bit_cast(bf16x8, *(const short8*)&As[(wr + fr) * 32 + kg * 8]);
    bf16x8 a1 = __builtin_bit_cast(bf16x8, *(const short8*)&As[(wr + 16 + fr) * 32 + kg * 8]);
    bf16x8 b0 = __builtin_bit_cast(bf16x8, *(const short8*)&Bs[(wc + fr) * 32 + kg * 8]);
    bf16x8 b1 = __builtin_bit_cast(bf16x8, *(const short8*)&Bs[(wc + 16 + fr) * 32 + kg * 8]);
    acc[0][0] = __builtin_amdgcn_mfma_f32_16x16x32_bf16(a0, b0, acc[0][0], 0, 0, 0);
    acc[0][1] = __builtin_amdgcn_mfma_f32_16x16x32_bf16(a0, b1, acc[0][1], 0, 0, 0);
    acc[1][0] = __builtin_amdgcn_mfma_f32_16x16x32_bf16(a1, b0, acc[1][0], 0, 0, 0);
    acc[1][1] = __builtin_amdgcn_mfma_f32_16x16x32_bf16(a1, b1, acc[1][1], 0, 0, 0);
    __syncthreads();
  }

  if (C)  C  += (size_t)z * sCz;
  if (Cb) Cb += (size_t)z * sCbz;
  #pragma unroll
  for (int i = 0; i < 2; i++)
    #pragma unroll
    for (int j = 0; j < 2; j++) {
      const int row_b = m0 + wr + i * 16 + kg * 4;
      const int col = n0 + wc + j * 16 + fr;
      #pragma unroll
      for (int r = 0; r < 4; r++) {
        const int row = row_b + r;
        float v = alpha * acc[i][j][r];
        if (flags & 1)  v = fminf(fmaxf(v, clo), chi);
        if (flags & 2)  v += bias[col];
        if (flags & 4)  v = fmaxf(v, 0.0f);
        if (flags & 8)  v += ((const float*)resid)[(size_t)row * ldr + col];
        if (flags & 32) v += bf2f_(((const u16*)resid)[(size_t)row * ldr + col]);
        if (flags & 64) { atomicAdd(&C[(size_t)row * ldc + col], v); continue; }
        if (flags & 16) v += C[(size_t)row * ldc + col];
        if (C)  C[(size_t)row * ldc + col] = v;
        if (Cb) Cb[(size_t)row * ldcb + col] = f2bf(v);
      }
    }
}

// ---------------------------------------------------------------------------
template<int NPER>
__global__ __launch_bounds__(256) void softmax_rows(
    const float* __restrict__ in, long ld_in, u16* __restrict__ out, long ld_out)
{
  const size_t row = blockIdx.x;
  const float* x = in + row * ld_in;
  u16* o = out + row * ld_out;
  const int t = threadIdx.x;
  float v[NPER];
  float mx = -1e30f;
  #pragma unroll
  for (int i = 0; i < NPER; i++) { v[i] = x[t + i * 256]; mx = fmaxf(mx, v[i]); }
  __shared__ float r1[4], r2[4];
  #pragma unroll
  for (int d = 32; d > 0; d >>= 1) mx = fmaxf(mx, __shfl_down(mx, d));
  if ((t & 63) == 0) r1[t >> 6] = mx;
  __syncthreads();
  mx = fmaxf(fmaxf(r1[0], r1[1]), fmaxf(r1[2], r1[3]));
  float s = 0.0f;
  #pragma unroll
  for (int i = 0; i < NPER; i++) { v[i] = __expf(v[i] - mx); s += v[i]; }
  #pragma unroll
  for (int d = 32; d > 0; d >>= 1) s += __shfl_down(s, d);
  if ((t & 63) == 0) r2[t >> 6] = s;
  __syncthreads();
  const float inv = 1.0f / (r2[0] + r2[1] + r2[2] + r2[3]);
  #pragma unroll
  for (int i = 0; i < NPER; i++) o[t + i * 256] = f2bf(v[i] * inv);
}

__global__ __launch_bounds__(256) void ln_plain_kernel(
    const float* __restrict__ in, float* __restrict__ outf, u16* __restrict__ outb)
{
  const size_t row = blockIdx.x;
  const float* x = in + row * D_;
  const int t = threadIdx.x;
  float a = x[t], b = x[t + 256];
  float s = a + b, ss = a * a + b * b;
  __shared__ float r1[4], r2[4];
  #pragma unroll
  for (int d = 32; d > 0; d >>= 1) { s += __shfl_down(s, d); ss += __shfl_down(ss, d); }
  if ((t & 63) == 0) { r1[t >> 6] = s; r2[t >> 6] = ss; }
  __syncthreads();
  s = r1[0] + r1[1] + r1[2] + r1[3];
  ss = r2[0] + r2[1] + r2[2] + r2[3];
  const float mu = s * (1.0f / D_);
  const float inv = rsqrtf(ss * (1.0f / D_) - mu * mu + 1e-5f);
  const float y0 = (a - mu) * inv, y1 = (b - mu) * inv;
  if (outf) { outf[row * D_ + t] = y0;       outf[row * D_ + t + 256] = y1; }
  if (outb) { outb[row * D_ + t] = f2bf(y0); outb[row * D_ + t + 256] = f2bf(y1); }
}

__global__ __launch_bounds__(256) void ln_affine_kernel(
    const float* __restrict__ in, const float* __restrict__ w, const float* __restrict__ b,
    float* __restrict__ outf, u16* __restrict__ outb)
{
  const size_t row = blockIdx.x;
  const float* x = in + row * D_;
  const int t = threadIdx.x;
  float a = x[t], c = x[t + 256];
  float s = a + c, ss = a * a + c * c;
  __shared__ float r1[4], r2[4];
  #pragma unroll
  for (int d = 32; d > 0; d >>= 1) { s += __shfl_down(s, d); ss += __shfl_down(ss, d); }
  if ((t & 63) == 0) { r1[t >> 6] = s; r2[t >> 6] = ss; }
  __syncthreads();
  s = r1[0] + r1[1] + r1[2] + r1[3];
  ss = r2[0] + r2[1] + r2[2] + r2[3];
  const float mu = s * (1.0f / D_);
  const float inv = rsqrtf(ss * (1.0f / D_) - mu * mu + 1e-5f);
  const float y0 = (a - mu) * inv * w[t] + b[t];
  const float y1 = (c - mu) * inv * w[t + 256] + b[t + 256];
  outf[row * D_ + t] = y0;       outf[row * D_ + t + 256] = y1;
  outb[row * D_ + t] = f2bf(y0); outb[row * D_ + t + 256] = f2bf(y1);
}

__global__ __launch_bounds__(256) void cvt_f2bf(
    const float* __restrict__ in, u16* __restrict__ out, size_t n)
{
  size_t i = (size_t)blockIdx.x * 256 + threadIdx.x;
  const size_t stride = (size_t)gridDim.x * 256;
  for (; i < n; i += stride) out[i] = f2bf(in[i]);
}

__global__ __launch_bounds__(256) void memfinal_kernel(
    const float* __restrict__ mem, float* __restrict__ io)
{
  const size_t i = (size_t)blockIdx.x * 256 + threadIdx.x;
  const size_t n4 = (size_t)L_ * MM_ * D_ / 4;
  if (i >= n4) return;
  const f32x4 m = ((const f32x4*)mem)[i];
  const f32x4 u = ((f32x4*)io)[i];
  f32x4 r;
  #pragma unroll
  for (int k = 0; k < 4; k++)
    r[k] = 0.9f * m[k] + fminf(fmaxf(0.1f * u[k], -0.1f), 0.1f);
  ((f32x4*)io)[i] = r;
}

__global__ __launch_bounds__(256) void pooled_reduce_kernel(
    const u16* __restrict__ outs, float* __restrict__ pooled)
{
  const int e = blockIdx.x, dc = blockIdx.y, nc = blockIdx.z;
  const int d = dc * 256 + threadIdx.x;
  const u16* p = outs + ((size_t)e * N_ + nc * 256) * D_ + d;
  float s = 0.0f;
  for (int i = 0; i < 256; i++) s += bf2f_(p[(size_t)i * D_]);
  atomicAdd(&pooled[e * D_ + d], s);
}

__global__ __launch_bounds__(256) void gate_kernel(
    const float* __restrict__ pooled, const float* __restrict__ gate,
    float* __restrict__ out_gw, float* __restrict__ ws_gw)
{
  const int t = threadIdx.x;
  const float g0 = gate[t], g1 = gate[t + 256];
  __shared__ float red[4][4];
  for (int e = 0; e < 4; e++) {
    float v = pooled[e * D_ + t] * g0 + pooled[e * D_ + t + 256] * g1;
    #pragma unroll
    for (int d = 32; d > 0; d >>= 1) v += __shfl_down(v, d);
    if ((t & 63) == 0) red[e][t >> 6] = v;
  }
  __syncthreads();
  if (t == 0) {
    float l[4], mx = -1e30f, sm = 0.0f;
    for (int e = 0; e < 4; e++) {
      l[e] = (red[e][0] + red[e][1] + red[e][2] + red[e][3]) * (1.0f / N_);
      l[e] = fminf(fmaxf(l[e], -10.0f), 10.0f);
      mx = fmaxf(mx, l[e]);
    }
    for (int e = 0; e < 4; e++) { l[e] = __expf(l[e] - mx); sm += l[e]; }
    for (int e = 0; e < 4; e++) { const float wv = l[e] / sm; out_gw[e] = wv; ws_gw[e] = wv; }
  }
}

__global__ __launch_bounds__(256) void fused_kernel(
    const u16* __restrict__ outs, const float* __restrict__ gw, float* __restrict__ out)
{
  const size_t i8 = ((size_t)blockIdx.x * 256 + threadIdx.x) * 8;
  const size_t s = (size_t)N_ * D_;
  if (i8 >= s) return;
  const float w0 = gw[0], w1 = gw[1], w2 = gw[2], w3 = gw[3];
  short8 v0 = *(const short8*)&outs[i8];
  short8 v1 = *(const short8*)&outs[i8 + s];
  short8 v2 = *(const short8*)&outs[i8 + 2 * s];
  short8 v3 = *(const short8*)&outs[i8 + 3 * s];
  float r[8];
  #pragma unroll
  for (int j = 0; j < 8; j++)
    r[j] = w0 * bf2f_((u16)v0[j]) + w1 * bf2f_((u16)v1[j]) +
           w2 * bf2f_((u16)v2[j]) + w3 * bf2f_((u16)v3[j]);
  *(f32x4*)&out[i8]     = *(f32x4*)&r[0];
  *(f32x4*)&out[i8 + 4] = *(f32x4*)&r[4];
}

// ---------------------------------------------------------------------------
extern "C" void kernel_launch(void* const* d_in, const int* in_sizes, int n_in,
                              void* d_out, int out_size, void* d_ws, size_t ws_size,
                              hipStream_t stream)
{
  (void)in_sizes; (void)n_in; (void)out_size; (void)ws_size;
  const float* tokens   = (const float*)d_in[0];
  const float* memories = (const float*)d_in[1];
  const float* ipw      = (const float*)d_in[2];
  const float* ipb      = (const float*)d_in[3];
  const float* opw      = (const float*)d_in[4];
  const float* opb      = (const float*)d_in[5];
  const float* w1       = (const float*)d_in[6];
  const float* b1       = (const float*)d_in[7];
  const float* w2       = (const float*)d_in[8];
  const float* b2       = (const float*)d_in[9];
  const float* n1w      = (const float*)d_in[10];
  const float* n1b      = (const float*)d_in[11];
  const float* n2w      = (const float*)d_in[12];
  const float* n2b      = (const float*)d_in[13];
  const float* aggw     = (const float*)d_in[14];
  const float* aggb     = (const float*)d_in[15];
  const float* ggate    = (const float*)d_in[16];

  float* out_fused = (float*)d_out;
  float* out_gate  = out_fused + (size_t)N_ * D_;
  float* out_mem   = out_gate + E_;          // [L][M][D], also the upd accumulator

  char* base = (char*)d_ws;
  size_t off = 0;
  auto alloc = [&](size_t b) -> char* {
    char* r = base + off; off += (b + 255) & ~(size_t)255; return r;
  };

  u16* xln_bf  = (u16*)alloc((size_t)E_ * N_ * D_ * 2);
  u16* mem_bf  = (u16*)alloc((size_t)L_ * MM_ * D_ * 2);
  u16* ipw_bf  = (u16*)alloc((size_t)E_ * 3 * D_ * D_ * 2);
  u16* opw_bf  = (u16*)alloc((size_t)E_ * D_ * D_ * 2);
  u16* w1_bf   = (u16*)alloc((size_t)E_ * FF_ * D_ * 2);
  u16* w2_bf   = (u16*)alloc((size_t)E_ * D_ * FF_ * 2);
  u16* agg_bf  = (u16*)alloc((size_t)D_ * L_ * D_ * 2);
  u16* outs_bf = (u16*)alloc((size_t)E_ * N_ * D_ * 2);
  float* pooled = (float*)alloc((size_t)E_ * D_ * 4);
  float* gatew  = (float*)alloc(256);
  // 32 MiB scratch union; internal layout (time-disjoint):
  //  cross scores [QC][3N] f32 = 24 MiB @ [0,24)
  //  self scores  [N][N]  f32 = 16 MiB @ [0,16);  sa32 [N][D] f32 4 MiB @ [16,20)
  //  pre [N][D] f32 @ [24,28);  x2 [N][D] f32 @ [28,32)
  //  mem logits [N][M] f32 = 32 MiB @ [0,32)
  char* scratch = alloc((size_t)N_ * MM_ * 4);
  float* scoresC = (float*)scratch;
  float* sscores = (float*)scratch;
  float* ml      = (float*)scratch;
  float* sa32    = (float*)(scratch + (16u << 20));
  float* pre     = (float*)(scratch + (24u << 20));
  float* x2      = (float*)(scratch + (28u << 20));
  float* x0f   = (float*)alloc((size_t)N_ * D_ * 4);
  float* x1    = (float*)alloc((size_t)N_ * D_ * 4);
  u16* x1_bf   = (u16*)alloc((size_t)N_ * D_ * 2);
  u16* qkv_bf  = (u16*)alloc((size_t)N_ * 3 * D_ * 2);
  u16* sa_bf   = (u16*)alloc((size_t)N_ * D_ * 2);
  u16* x2_bf   = (u16*)alloc((size_t)N_ * D_ * 2);
  u16* ff1_bf  = (u16*)alloc((size_t)N_ * FF_ * 2);
  u16* retr_bf = ff1_bf;                                    // phase-disjoint union
  float* x3    = (float*)alloc((size_t)N_ * D_ * 4);
  u16* x3_bf   = (u16*)alloc((size_t)N_ * D_ * 2);

  auto GB = [&](int BN, dim3 grid,
                const u16* A, int lda, long a1, long a2,
                const u16* B, int ldb, long b1, long b2,
                float* C, int ldc, long cz, u16* Cb, int ldcb, long cbz,
                const float* bias, const void* resid, int ldr,
                int K, int zdiv, float alpha, float clo, float chi, int flags) {
    if (BN == 128)
      gemm_big<128><<<grid, 256, 0, stream>>>(A, lda, a1, a2, B, ldb, b1, b2,
          C, ldc, cz, Cb, ldcb, cbz, bias, resid, ldr, K, zdiv, alpha, clo, chi, flags);
    else
      gemm_big<64><<<grid, 256, 0, stream>>>(A, lda, a1, a2, B, ldb, b1, b2,
          C, ldc, cz, Cb, ldcb, cbz, bias, resid, ldr, K, zdiv, alpha, clo, chi, flags);
  };
  auto G64 = [&](int ta, int tb, dim3 grid,
                 const u16* A, int lda, long a1, long a2,
                 const u16* B, int ldb, long b1, long b2,
                 float* C, int ldc, long cz, u16* Cb, int ldcb, long cbz,
                 const float* bias, const void* resid, int ldr,
                 int K, int zdiv, float alpha, float clo, float chi, int flags) {
    if (ta == 0 && tb == 0)
      gemm_k<0,0><<<grid, 256, 0, stream>>>(A, lda, a1, a2, B, ldb, b1, b2,
          C, ldc, cz, Cb, ldcb, cbz, bias, resid, ldr, K, zdiv, alpha, clo, chi, flags);
    else if (ta == 0 && tb == 1)
      gemm_k<0,1><<<grid, 256, 0, stream>>>(A, lda, a1, a2, B, ldb, b1, b2,
          C, ldc, cz, Cb, ldcb, cbz, bias, resid, ldr, K, zdiv, alpha, clo, chi, flags);
    else
      gemm_k<1,1><<<grid, 256, 0, stream>>>(A, lda, a1, a2, B, ldb, b1, b2,
          C, ldc, cz, Cb, ldcb, cbz, bias, resid, ldr, K, zdiv, alpha, clo, chi, flags);
  };

  const float inv_sqrt_d = 0.04419417382415922f;  // 1/sqrt(512)
  const long ND = (long)N_ * D_;

  hipMemsetAsync(out_mem, 0, (size_t)L_ * MM_ * D_ * 4, stream);
  hipMemsetAsync(pooled, 0, (size_t)E_ * D_ * 4, stream);

  ln_plain_kernel<<<E_ * N_, 256, 0, stream>>>(tokens, nullptr, xln_bf);
  cvt_f2bf<<<2048, 256, 0, stream>>>(memories, mem_bf, (size_t)L_ * MM_ * D_);
  cvt_f2bf<<<2048, 256, 0, stream>>>(ipw, ipw_bf, (size_t)E_ * 3 * D_ * D_);
  cvt_f2bf<<<1024, 256, 0, stream>>>(opw, opw_bf, (size_t)E_ * D_ * D_);
  cvt_f2bf<<<2048, 256, 0, stream>>>(w1, w1_bf, (size_t)E_ * FF_ * D_);
  cvt_f2bf<<<2048, 256, 0, stream>>>(w2, w2_bf, (size_t)E_ * D_ * FF_);
  cvt_f2bf<<<1024, 256, 0, stream>>>(aggw, agg_bf, (size_t)D_ * L_ * D_);

  for (int e = 0; e < E_; e++) {
    ln_plain_kernel<<<N_, 256, 0, stream>>>(tokens + (size_t)e * N_ * D_, x0f, nullptr);

    // ---- cross-expert attention (2 query chunks; z over context experts) ----
    for (int cc = 0; cc < 2; cc++) {
      const int q0 = cc * QC_;
      const u16* xq = xln_bf + ((size_t)e * N_ + q0) * D_;
      if (e > 0)   // js 0..e-1 -> score cols [0, e*N)
        GB(128, dim3(16, QC_ / 128, e), xq, D_, 0, 0, xln_bf, D_, 0, ND,
           scoresC, 3 * N_, N_, nullptr, 0, 0, nullptr, nullptr, 0,
           D_, 64, inv_sqrt_d, -10.0f, 10.0f, 1);
      if (e < 3)   // js e+1..3 -> score cols [e*N, 3N)
        GB(128, dim3(16, QC_ / 128, 3 - e), xq, D_, 0, 0,
           xln_bf + (size_t)(e + 1) * ND, D_, 0, ND,
           scoresC + (size_t)e * N_, 3 * N_, N_, nullptr, 0, 0, nullptr, nullptr, 0,
           D_, 64, inv_sqrt_d, -10.0f, 10.0f, 1);
      softmax_rows<24><<<QC_, 256, 0, stream>>>(scoresC, 3 * N_, (u16*)scoresC, 2L * 3 * N_);
      for (int s = 0; s < 3; s++) {
        const int js = (s < e) ? s : s + 1;
        G64(0, 1, dim3(8, QC_ / 64, 1),
            (const u16*)scoresC + (size_t)s * N_, 2 * 3 * N_, 0, 0,
            xln_bf + (size_t)js * ND, D_, 0, 0,
            x1 + (size_t)q0 * D_, D_, 0,
            (s == 2) ? x1_bf + (size_t)q0 * D_ : nullptr, D_, 0,
            nullptr, (s == 0) ? (const void*)(x0f + (size_t)q0 * D_) : nullptr, D_,
            N_, 64, 1.0f, 0, 0, (s == 0) ? 8 : 16);
      }
    }

    // ---- encoder layer ----
    GB(128, dim3(12, 16, 1), x1_bf, D_, 0, 0, ipw_bf + (size_t)e * 3 * D_ * D_, D_, 0, 0,
       nullptr, 0, 0, qkv_bf, 3 * D_, 0, ipb + (size_t)e * 3 * D_, nullptr, 0,
       D_, 64, 1.0f, 0, 0, 2);
    hipMemsetAsync(sa32, 0, (size_t)N_ * D_ * 4, stream);
    for (int h = 0; h < H_; h++) {
      GB(128, dim3(16, 16, 1), qkv_bf + h * DH_, 3 * D_, 0, 0,
         qkv_bf + D_ + h * DH_, 3 * D_, 0, 0,
         sscores, N_, 0, nullptr, 0, 0, nullptr, nullptr, 0,
         DH_, 64, 0.125f, 0, 0, 0);
      softmax_rows<8><<<N_, 256, 0, stream>>>(sscores, N_, (u16*)sscores, 2L * N_);
      // PV with 8-way split-K, atomic f32 accumulate
      G64(0, 1, dim3(1, 32, 8), (const u16*)sscores, 2 * N_, 0, 256,
          qkv_bf + 2 * D_ + h * DH_, 3 * D_, 0, 256L * 3 * D_,
          sa32 + h * DH_, D_, 0, nullptr, 0, 0, nullptr, nullptr, 0,
          256, 64, 1.0f, 0, 0, 64);
    }
    cvt_f2bf<<<1024, 256, 0, stream>>>(sa32, sa_bf, (size_t)N_ * D_);
    G64(0, 0, dim3(8, 32, 1), sa_bf, D_, 0, 0, opw_bf + (size_t)e * D_ * D_, D_, 0, 0,
        pre, D_, 0, nullptr, 0, 0, opb + (size_t)e * D_, x1, D_,
        D_, 64, 1.0f, 0, 0, 2 | 8);
    ln_affine_kernel<<<N_, 256, 0, stream>>>(pre, n1w + (size_t)e * D_, n1b + (size_t)e * D_, x2, x2_bf);
    GB(128, dim3(16, 16, 1), x2_bf, D_, 0, 0, w1_bf + (size_t)e * FF_ * D_, D_, 0, 0,
       nullptr, 0, 0, ff1_bf, FF_, 0, b1 + (size_t)e * FF_, nullptr, 0,
       D_, 64, 1.0f, 0, 0, 2 | 4);
    GB(64, dim3(8, 16, 1), ff1_bf, FF_, 0, 0, w2_bf + (size_t)e * D_ * FF_, FF_, 0, 0,
       pre, D_, 0, nullptr, 0, 0, b2 + (size_t)e * D_, x2, D_,
       FF_, 64, 1.0f, 0, 0, 2 | 8);
    ln_affine_kernel<<<N_, 256, 0, stream>>>(pre, n2w + (size_t)e * D_, n2b + (size_t)e * D_, x3, x3_bf);

    // ---- hierarchical memory ----
    for (int l = 0; l < L_; l++) {
      GB(128, dim3(32, 16, 1), x3_bf, D_, 0, 0, mem_bf + (size_t)l * MM_ * D_, D_, 0, 0,
         ml, MM_, 0, nullptr, 0, 0, nullptr, nullptr, 0,
         D_, 64, inv_sqrt_d, -10.0f, 10.0f, 1);
      softmax_rows<16><<<N_, 256, 0, stream>>>(ml, MM_, (u16*)ml, 2L * MM_);
      G64(0, 1, dim3(8, 32, 1), (const u16*)ml, 2 * MM_, 0, 0,
          mem_bf + (size_t)l * MM_ * D_, D_, 0, 0,
          nullptr, 0, 0, retr_bf + l * D_, L_ * D_, 0, nullptr, nullptr, 0,
          MM_, 64, 1.0f, 0, 0, 0);
      G64(1, 1, dim3(8, 64, 1), (const u16*)ml, 2 * MM_, 0, 0, x3_bf, D_, 0, 0,
          out_mem + (size_t)l * MM_ * D_, D_, 0, nullptr, 0, 0, nullptr, nullptr, 0,
          N_, 64, 1.0f, -1.0f, 1.0f, 1 | 16);
    }
    GB(64, dim3(8, 16, 1), retr_bf, L_ * D_, 0, 0, agg_bf, L_ * D_, 0, 0,
       nullptr, 0, 0, outs_bf + (size_t)e * N_ * D_, D_, 0, aggb, x3, D_,
       L_ * D_, 64, 1.0f, 0, 0, 2 | 8);
  }

  // ---- memory EMA + global fusion ----
  memfinal_kernel<<<(L_ * MM_ * D_ / 4 + 255) / 256, 256, 0, stream>>>(memories, out_mem);
  pooled_reduce_kernel<<<dim3(E_, D_ / 256, N_ / 256), 256, 0, stream>>>(outs_bf, pooled);
  gate_kernel<<<1, 256, 0, stream>>>(pooled, ggate, out_gate, gatew);
  fused_kernel<<<512, 256, 0, stream>>>(outs_bf, gatew, out_fused);
}

// Round 5
// 5642.774 us; speedup vs baseline: 1.1952x; 1.1034x over previous
//
#include <hip/hip_runtime.h>
#include <stdint.h>

#define E_ 4
#define N_ 2048
#define D_ 512
#define H_ 8
#define DH_ 64
#define FF_ 2048
#define L_ 4
#define MM_ 4096
#define QC_ 1024   // cross-attn query chunk rows

typedef unsigned short u16;
typedef __attribute__((ext_vector_type(8))) short short8;
typedef __attribute__((ext_vector_type(8))) __bf16 bf16x8;
typedef __attribute__((ext_vector_type(4))) float f32x4;

__device__ __forceinline__ u16 f2bf(float f) {
  uint32_t u = __builtin_bit_cast(uint32_t, f);
  u = (u + 0x7fffu + ((u >> 16) & 1u)) >> 16;
  return (u16)u;
}
__device__ __forceinline__ float bf2f_(u16 h) {
  uint32_t u = ((uint32_t)h) << 16;
  return __builtin_bit_cast(float, u);
}
__device__ __forceinline__ float to_f(float x) { return x; }
__device__ __forceinline__ float to_f(u16 x) { return bf2f_(x); }

typedef __attribute__((address_space(3))) char lds_char;
typedef __attribute__((address_space(1))) const char glb_char;
__device__ __forceinline__ void glds16(const void* g, void* l) {
  __builtin_amdgcn_global_load_lds((glb_char*)g, (lds_char*)l, 16, 0, 0);
}

// ---------------------------------------------------------------------------
// gemm_big<BN, TA>: C[M,N] = epi(alpha * op(A) @ B^T). Tile 128 x BN, BK=32.
//   TA=0: A stored [M][K] (glds staging). TA=1: A stored [K][M] (vector load,
//         scalar LDS write staging).  B always [N][K] (glds).
// flags: 1=CLIP 2=BIAS(col) 4=RELU 8=RESID f32 16=ACCUM(+C) 32=RESID bf16
//        64=ATOMIC-ADD into C (f32) — exclusive with stores
// All operands offset by z: P += (z/zdiv)*sPz1 + (z%zdiv)*sPz2  (elements).
// ---------------------------------------------------------------------------
template<int BN, int TA>
__global__ __launch_bounds__(256) void gemm_big(
    const u16* __restrict__ A, int lda, long sAz1, long sAz2,
    const u16* __restrict__ B, int ldb, long sBz1, long sBz2,
    float* __restrict__ C, int ldc, long sCz1, long sCz2,
    u16* __restrict__ Cb, int ldcb, long sCbz,
    const float* __restrict__ bias, const void* __restrict__ resid, int ldr,
    int K, int zdiv, float alpha, float clo, float chi, int flags)
{
  __shared__ u16 As[128 * 32];
  __shared__ u16 Bs[BN * 32];
  const int z = blockIdx.z, zq = z / zdiv, zr = z % zdiv;
  A += (size_t)zq * sAz1 + (size_t)zr * sAz2;
  B += (size_t)zq * sBz1 + (size_t)zr * sBz2;
  const int m0 = blockIdx.y * 128, n0 = blockIdx.x * BN;
  const int t = threadIdx.x, lane = t & 63, w = t >> 6;
  constexpr int NI = (BN == 128) ? 4 : 2;
  const int WR = (BN == 128) ? ((w >> 1) * 64) : (w * 32);
  const int WC = (BN == 128) ? ((w & 1) * 64) : 0;
  const int fr = lane & 15, kg = lane >> 4;
  const int srw = lane >> 2, sck = (lane & 3) << 3;
  // TA=1 staging coords
  const int kr = t & 31, mg = (t >> 5) << 4;

  const u16 *gA0, *gA1 = nullptr;
  if constexpr (TA == 0) {
    gA0 = A + (size_t)(m0 + w * 16 + srw) * lda + sck;
    gA1 = A + (size_t)(m0 + 64 + w * 16 + srw) * lda + sck;
  } else {
    gA0 = A + (size_t)kr * lda + m0 + mg;
  }
  const u16* gB0 = B + (size_t)(n0 + w * 16 + srw) * ldb + sck;
  const u16* gB1 = nullptr;
  if constexpr (BN == 128) gB1 = B + (size_t)(n0 + 64 + w * 16 + srw) * ldb + sck;
  u16* lA0 = &As[(w * 16) * 32];
  u16* lA1 = &As[(64 + w * 16) * 32];
  u16* lB0 = &Bs[(w * 16) * 32];
  u16* lB1 = nullptr;
  if constexpr (BN == 128) lB1 = &Bs[(64 + w * 16) * 32];

  f32x4 acc[NI][4];
  #pragma unroll
  for (int i = 0; i < NI; i++)
    #pragma unroll
    for (int j = 0; j < 4; j++)
      #pragma unroll
      for (int r = 0; r < 4; r++) acc[i][j][r] = 0.0f;

  for (int k0 = 0; k0 < K; k0 += 32) {
    if constexpr (TA == 0) {
      glds16(gA0, lA0); glds16(gA1, lA1);
      gA0 += 32; gA1 += 32;
    } else {
      short8 v0 = *(const short8*)gA0;
      short8 v1 = *(const short8*)(gA0 + 8);
      gA0 += (size_t)32 * lda;
      #pragma unroll
      for (int j = 0; j < 8; j++) As[(mg + j) * 32 + kr] = (u16)v0[j];
      #pragma unroll
      for (int j = 0; j < 8; j++) As[(mg + 8 + j) * 32 + kr] = (u16)v1[j];
    }
    glds16(gB0, lB0); gB0 += 32;
    if constexpr (BN == 128) { glds16(gB1, lB1); gB1 += 32; }
    __syncthreads();
    bf16x8 af[NI], bfr[4];
    #pragma unroll
    for (int i = 0; i < NI; i++)
      af[i] = __builtin_bit_cast(bf16x8, *(const short8*)&As[(WR + i * 16 + fr) * 32 + kg * 8]);
    #pragma unroll
    for (int j = 0; j < 4; j++)
      bfr[j] = __builtin_bit_cast(bf16x8, *(const short8*)&Bs[(WC + j * 16 + fr) * 32 + kg * 8]);
    #pragma unroll
    for (int i = 0; i < NI; i++)
      #pragma unroll
      for (int j = 0; j < 4; j++)
        acc[i][j] = __builtin_amdgcn_mfma_f32_16x16x32_bf16(af[i], bfr[j], acc[i][j], 0, 0, 0);
    __syncthreads();
  }

  if (C)  C  += (size_t)zq * sCz1 + (size_t)zr * sCz2;
  if (Cb) Cb += (size_t)z * sCbz;
  #pragma unroll
  for (int i = 0; i < NI; i++)
    #pragma unroll
    for (int j = 0; j < 4; j++) {
      const int row_b = m0 + WR + i * 16 + kg * 4;
      const int col = n0 + WC + j * 16 + fr;
      #pragma unroll
      for (int r = 0; r < 4; r++) {
        const int row = row_b + r;
        float v = alpha * acc[i][j][r];
        if (flags & 1)  v = fminf(fmaxf(v, clo), chi);
        if (flags & 2)  v += bias[col];
        if (flags & 4)  v = fmaxf(v, 0.0f);
        if (flags & 8)  v += ((const float*)resid)[(size_t)row * ldr + col];
        if (flags & 32) v += bf2f_(((const u16*)resid)[(size_t)row * ldr + col]);
        if (flags & 64) { atomicAdd(&C[(size_t)row * ldc + col], v); continue; }
        if (flags & 16) v += C[(size_t)row * ldc + col];
        if (C)  C[(size_t)row * ldc + col] = v;
        if (Cb) Cb[(size_t)row * ldcb + col] = f2bf(v);
      }
    }
}

// ---------------------------------------------------------------------------
// Row softmax, len = NPER*256, f32 in -> bf16 out (in-place safe: same stride)
// ---------------------------------------------------------------------------
template<int NPER>
__global__ __launch_bounds__(256) void softmax_rows(
    const float* __restrict__ in, long ld_in, u16* __restrict__ out, long ld_out)
{
  const size_t row = blockIdx.x;
  const float* x = in + row * ld_in;
  u16* o = out + row * ld_out;
  const int t = threadIdx.x;
  float v[NPER];
  float mx = -1e30f;
  #pragma unroll
  for (int i = 0; i < NPER; i++) { v[i] = x[t + i * 256]; mx = fmaxf(mx, v[i]); }
  __shared__ float r1[4], r2[4];
  #pragma unroll
  for (int d = 32; d > 0; d >>= 1) mx = fmaxf(mx, __shfl_down(mx, d));
  if ((t & 63) == 0) r1[t >> 6] = mx;
  __syncthreads();
  mx = fmaxf(fmaxf(r1[0], r1[1]), fmaxf(r1[2], r1[3]));
  float s = 0.0f;
  #pragma unroll
  for (int i = 0; i < NPER; i++) { v[i] = __expf(v[i] - mx); s += v[i]; }
  #pragma unroll
  for (int d = 32; d > 0; d >>= 1) s += __shfl_down(s, d);
  if ((t & 63) == 0) r2[t >> 6] = s;
  __syncthreads();
  const float inv = 1.0f / (r2[0] + r2[1] + r2[2] + r2[3]);
  #pragma unroll
  for (int i = 0; i < NPER; i++) o[t + i * 256] = f2bf(v[i] * inv);
}

// ---------------------------------------------------------------------------
__global__ __launch_bounds__(256) void ln_plain_kernel(
    const float* __restrict__ in, float* __restrict__ outf, u16* __restrict__ outb)
{
  const size_t row = blockIdx.x;
  const float* x = in + row * D_;
  const int t = threadIdx.x;
  float a = x[t], b = x[t + 256];
  float s = a + b, ss = a * a + b * b;
  __shared__ float r1[4], r2[4];
  #pragma unroll
  for (int d = 32; d > 0; d >>= 1) { s += __shfl_down(s, d); ss += __shfl_down(ss, d); }
  if ((t & 63) == 0) { r1[t >> 6] = s; r2[t >> 6] = ss; }
  __syncthreads();
  s = r1[0] + r1[1] + r1[2] + r1[3];
  ss = r2[0] + r2[1] + r2[2] + r2[3];
  const float mu = s * (1.0f / D_);
  const float inv = rsqrtf(ss * (1.0f / D_) - mu * mu + 1e-5f);
  const float y0 = (a - mu) * inv, y1 = (b - mu) * inv;
  if (outf) { outf[row * D_ + t] = y0;       outf[row * D_ + t + 256] = y1; }
  if (outb) { outb[row * D_ + t] = f2bf(y0); outb[row * D_ + t + 256] = f2bf(y1); }
}

__global__ __launch_bounds__(256) void ln_affine_kernel(
    const float* __restrict__ in, const float* __restrict__ w, const float* __restrict__ b,
    float* __restrict__ outf, u16* __restrict__ outb)
{
  const size_t row = blockIdx.x;
  const float* x = in + row * D_;
  const int t = threadIdx.x;
  float a = x[t], c = x[t + 256];
  float s = a + c, ss = a * a + c * c;
  __shared__ float r1[4], r2[4];
  #pragma unroll
  for (int d = 32; d > 0; d >>= 1) { s += __shfl_down(s, d); ss += __shfl_down(ss, d); }
  if ((t & 63) == 0) { r1[t >> 6] = s; r2[t >> 6] = ss; }
  __syncthreads();
  s = r1[0] + r1[1] + r1[2] + r1[3];
  ss = r2[0] + r2[1] + r2[2] + r2[3];
  const float mu = s * (1.0f / D_);
  const float inv = rsqrtf(ss * (1.0f / D_) - mu * mu + 1e-5f);
  const float y0 = (a - mu) * inv * w[t] + b[t];
  const float y1 = (c - mu) * inv * w[t + 256] + b[t + 256];
  if (outf) { outf[row * D_ + t] = y0;       outf[row * D_ + t + 256] = y1; }
  outb[row * D_ + t] = f2bf(y0); outb[row * D_ + t + 256] = f2bf(y1);
}

// ---------------------------------------------------------------------------
// Tiled transpose -> bf16: out[c][r] = bf16(in[r][c]); grid(cols/32, rows/32, z)
// ---------------------------------------------------------------------------
template<typename T>
__global__ __launch_bounds__(256) void transpose_to_bf16(
    const T* __restrict__ in, long in_batch, int ld_in,
    u16* __restrict__ out, long out_batch, int ld_out)
{
  __shared__ float tile[32][33];
  const int z = blockIdx.z;
  in  += (size_t)z * in_batch;
  out += (size_t)z * out_batch;
  const int c0 = blockIdx.x << 5, r0 = blockIdx.y << 5;
  const int tx = threadIdx.x & 31, ty = threadIdx.x >> 5;
  #pragma unroll
  for (int k = 0; k < 4; k++)
    tile[ty + 8 * k][tx] = to_f(in[(size_t)(r0 + ty + 8 * k) * ld_in + c0 + tx]);
  __syncthreads();
  #pragma unroll
  for (int k = 0; k < 4; k++)
    out[(size_t)(c0 + ty + 8 * k) * ld_out + r0 + tx] = f2bf(tile[tx][ty + 8 * k]);
}

__global__ __launch_bounds__(256) void cvt_f2bf(
    const float* __restrict__ in, u16* __restrict__ out, size_t n)
{
  size_t i = (size_t)blockIdx.x * 256 + threadIdx.x;
  const size_t stride = (size_t)gridDim.x * 256;
  for (; i < n; i += stride) out[i] = f2bf(in[i]);
}

__global__ __launch_bounds__(256) void memfinal_kernel(
    const float* __restrict__ mem, float* __restrict__ io)
{
  const size_t i = (size_t)blockIdx.x * 256 + threadIdx.x;
  const size_t n4 = (size_t)L_ * MM_ * D_ / 4;
  if (i >= n4) return;
  const f32x4 m = ((const f32x4*)mem)[i];
  const f32x4 u = ((f32x4*)io)[i];
  f32x4 r;
  #pragma unroll
  for (int k = 0; k < 4; k++)
    r[k] = 0.9f * m[k] + fminf(fmaxf(0.1f * u[k], -0.1f), 0.1f);
  ((f32x4*)io)[i] = r;
}

__global__ __launch_bounds__(256) void pooled_reduce_kernel(
    const u16* __restrict__ outs, float* __restrict__ pooled)
{
  const int e = blockIdx.x, dc = blockIdx.y, nc = blockIdx.z;
  const int d = dc * 256 + threadIdx.x;
  const u16* p = outs + ((size_t)e * N_ + nc * 256) * D_ + d;
  float s = 0.0f;
  for (int i = 0; i < 256; i++) s += bf2f_(p[(size_t)i * D_]);
  atomicAdd(&pooled[e * D_ + d], s);
}

__global__ __launch_bounds__(256) void gate_kernel(
    const float* __restrict__ pooled, const float* __restrict__ gate,
    float* __restrict__ out_gw, float* __restrict__ ws_gw)
{
  const int t = threadIdx.x;
  const float g0 = gate[t], g1 = gate[t + 256];
  __shared__ float red[4][4];
  for (int e = 0; e < 4; e++) {
    float v = pooled[e * D_ + t] * g0 + pooled[e * D_ + t + 256] * g1;
    #pragma unroll
    for (int d = 32; d > 0; d >>= 1) v += __shfl_down(v, d);
    if ((t & 63) == 0) red[e][t >> 6] = v;
  }
  __syncthreads();
  if (t == 0) {
    float l[4], mx = -1e30f, sm = 0.0f;
    for (int e = 0; e < 4; e++) {
      l[e] = (red[e][0] + red[e][1] + red[e][2] + red[e][3]) * (1.0f / N_);
      l[e] = fminf(fmaxf(l[e], -10.0f), 10.0f);
      mx = fmaxf(mx, l[e]);
    }
    for (int e = 0; e < 4; e++) { l[e] = __expf(l[e] - mx); sm += l[e]; }
    for (int e = 0; e < 4; e++) { const float wv = l[e] / sm; out_gw[e] = wv; ws_gw[e] = wv; }
  }
}

__global__ __launch_bounds__(256) void fused_kernel(
    const u16* __restrict__ outs, const float* __restrict__ gw, float* __restrict__ out)
{
  const size_t i8 = ((size_t)blockIdx.x * 256 + threadIdx.x) * 8;
  const size_t s = (size_t)N_ * D_;
  if (i8 >= s) return;
  const float w0 = gw[0], w1 = gw[1], w2 = gw[2], w3 = gw[3];
  short8 v0 = *(const short8*)&outs[i8];
  short8 v1 = *(const short8*)&outs[i8 + s];
  short8 v2 = *(const short8*)&outs[i8 + 2 * s];
  short8 v3 = *(const short8*)&outs[i8 + 3 * s];
  float r[8];
  #pragma unroll
  for (int j = 0; j < 8; j++)
    r[j] = w0 * bf2f_((u16)v0[j]) + w1 * bf2f_((u16)v1[j]) +
           w2 * bf2f_((u16)v2[j]) + w3 * bf2f_((u16)v3[j]);
  *(f32x4*)&out[i8]     = *(f32x4*)&r[0];
  *(f32x4*)&out[i8 + 4] = *(f32x4*)&r[4];
}

// ---------------------------------------------------------------------------
extern "C" void kernel_launch(void* const* d_in, const int* in_sizes, int n_in,
                              void* d_out, int out_size, void* d_ws, size_t ws_size,
                              hipStream_t stream)
{
  (void)in_sizes; (void)n_in; (void)out_size; (void)ws_size;
  const float* tokens   = (const float*)d_in[0];
  const float* memories = (const float*)d_in[1];
  const float* ipw      = (const float*)d_in[2];
  const float* ipb      = (const float*)d_in[3];
  const float* opw      = (const float*)d_in[4];
  const float* opb      = (const float*)d_in[5];
  const float* w1       = (const float*)d_in[6];
  const float* b1       = (const float*)d_in[7];
  const float* w2       = (const float*)d_in[8];
  const float* b2       = (const float*)d_in[9];
  const float* n1w      = (const float*)d_in[10];
  const float* n1b      = (const float*)d_in[11];
  const float* n2w      = (const float*)d_in[12];
  const float* n2b      = (const float*)d_in[13];
  const float* aggw     = (const float*)d_in[14];
  const float* aggb     = (const float*)d_in[15];
  const float* ggate    = (const float*)d_in[16];

  float* out_fused = (float*)d_out;
  float* out_gate  = out_fused + (size_t)N_ * D_;
  float* out_mem   = out_gate + E_;          // [L][M][D], also the upd accumulator

  char* base = (char*)d_ws;
  size_t off = 0;
  auto alloc = [&](size_t b) -> char* {
    char* r = base + off; off += (b + 255) & ~(size_t)255; return r;
  };

  // persistent (~60.9 MB)
  u16* xln_bf  = (u16*)alloc((size_t)E_ * N_ * D_ * 2);
  u16* xlnT_bf = (u16*)alloc((size_t)E_ * D_ * N_ * 2);
  u16* mem_bf  = (u16*)alloc((size_t)L_ * MM_ * D_ * 2);
  u16* memT_bf = (u16*)alloc((size_t)L_ * D_ * MM_ * 2);
  u16* agg_bf  = (u16*)alloc((size_t)D_ * L_ * D_ * 2);
  u16* outs_bf = (u16*)alloc((size_t)E_ * N_ * D_ * 2);
  float* pooled = (float*)alloc((size_t)E_ * D_ * 4);
  float* gatew  = (float*)alloc(256);
  // per-expert weights (converted per expert, ~6.3 MB)
  u16* ipw_e = (u16*)alloc((size_t)3 * D_ * D_ * 2);
  u16* opw_e = (u16*)alloc((size_t)D_ * D_ * 2);
  u16* w1_e  = (u16*)alloc((size_t)FF_ * D_ * 2);
  u16* w2_e  = (u16*)alloc((size_t)D_ * FF_ * 2);
  // per-expert activations (~29.4 MB)
  float* x1   = (float*)alloc((size_t)N_ * D_ * 4);    // LN residual + cross-PV accum
  u16* x1_bf  = (u16*)alloc((size_t)N_ * D_ * 2);
  u16* vT_bf  = (u16*)alloc((size_t)D_ * N_ * 2);      // vT | x3T (time-disjoint)
  u16* x3T_bf = vT_bf;
  u16* sa_bf  = (u16*)alloc((size_t)N_ * D_ * 2);
  u16* x2_bf  = (u16*)alloc((size_t)N_ * D_ * 2);
  u16* qkv_bf = (u16*)alloc((size_t)N_ * FF_ * 2);     // qkv | ff1 | retr (disjoint)
  u16* ff1_bf = qkv_bf;
  u16* retr_bf= qkv_bf;
  float* x3   = (float*)alloc((size_t)N_ * D_ * 4);    // sa32 | x3 (time-disjoint)
  float* sa32 = x3;
  u16* x3_bf  = (u16*)alloc((size_t)N_ * D_ * 2);
  // region A, 33.55 MB (phase-disjoint):
  //  cross: scoresC [QC][3N] f32 (25.2)
  //  self:  sscores [2][N][N] f32 (33.55)
  //  post-self: x2f @0 (4.19), pre @8388608B (4.19)
  //  memory: ml [N][MM] f32 (33.55)
  char* RA = alloc((size_t)N_ * MM_ * 4);
  float* scoresC = (float*)RA;
  float* sscores = (float*)RA;
  float* ml      = (float*)RA;
  float* x2f     = (float*)RA;
  float* pre     = (float*)(RA + 8388608);

  auto G = [&](int BN, int TA, dim3 grid,
               const u16* A, int lda, long a1, long a2,
               const u16* B, int ldb, long b1, long b2,
               float* C, int ldc, long c1, long c2,
               u16* Cb, int ldcb, long cbz,
               const float* bias, const void* resid, int ldr,
               int K, int zdiv, float alpha, float clo, float chi, int flags) {
    if (BN == 128 && TA == 0)
      gemm_big<128,0><<<grid, 256, 0, stream>>>(A, lda, a1, a2, B, ldb, b1, b2,
          C, ldc, c1, c2, Cb, ldcb, cbz, bias, resid, ldr, K, zdiv, alpha, clo, chi, flags);
    else if (BN == 128 && TA == 1)
      gemm_big<128,1><<<grid, 256, 0, stream>>>(A, lda, a1, a2, B, ldb, b1, b2,
          C, ldc, c1, c2, Cb, ldcb, cbz, bias, resid, ldr, K, zdiv, alpha, clo, chi, flags);
    else
      gemm_big<64,0><<<grid, 256, 0, stream>>>(A, lda, a1, a2, B, ldb, b1, b2,
          C, ldc, c1, c2, Cb, ldcb, cbz, bias, resid, ldr, K, zdiv, alpha, clo, chi, flags);
  };

  const float isd = 0.04419417382415922f;  // 1/sqrt(512)
  const long ND = (long)N_ * D_;
  const long DN = (long)D_ * N_;

  hipMemsetAsync(out_mem, 0, (size_t)L_ * MM_ * D_ * 4, stream);
  hipMemsetAsync(pooled, 0, (size_t)E_ * D_ * 4, stream);

  // ---- setup: LN all tokens -> bf16; transposes; memory cvt ----
  ln_plain_kernel<<<E_ * N_, 256, 0, stream>>>(tokens, nullptr, xln_bf);
  transpose_to_bf16<u16><<<dim3(D_ / 32, N_ / 32, E_), 256, 0, stream>>>(
      xln_bf, ND, D_, xlnT_bf, DN, N_);
  cvt_f2bf<<<2048, 256, 0, stream>>>(memories, mem_bf, (size_t)L_ * MM_ * D_);
  transpose_to_bf16<float><<<dim3(D_ / 32, MM_ / 32, L_), 256, 0, stream>>>(
      memories, (long)MM_ * D_, D_, memT_bf, (long)D_ * MM_, MM_);
  cvt_f2bf<<<1024, 256, 0, stream>>>(aggw, agg_bf, (size_t)D_ * L_ * D_);

  for (int e = 0; e < E_; e++) {
    // per-expert weight conversion
    cvt_f2bf<<<768, 256, 0, stream>>>(ipw + (size_t)e * 3 * D_ * D_, ipw_e, (size_t)3 * D_ * D_);
    cvt_f2bf<<<256, 256, 0, stream>>>(opw + (size_t)e * D_ * D_, opw_e, (size_t)D_ * D_);
    cvt_f2bf<<<1024, 256, 0, stream>>>(w1 + (size_t)e * FF_ * D_, w1_e, (size_t)FF_ * D_);
    cvt_f2bf<<<1024, 256, 0, stream>>>(w2 + (size_t)e * D_ * FF_, w2_e, (size_t)D_ * FF_);
    // f32 LN of this expert's tokens into x1 (acts as PV residual base)
    ln_plain_kernel<<<N_, 256, 0, stream>>>(tokens + (size_t)e * N_ * D_, x1, nullptr);

    // ---- cross-expert attention (2 query chunks of 1024) ----
    for (int cc = 0; cc < 2; cc++) {
      const int q0 = cc * QC_;
      const u16* xq = xln_bf + ((size_t)e * N_ + q0) * D_;
      if (e > 0)   // ctx experts 0..e-1 -> score cols [0, e*N)
        G(128, 0, dim3(16, QC_ / 128, e), xq, D_, 0, 0, xln_bf, D_, ND, 0,
          scoresC, 3 * N_, N_, 0, nullptr, 0, 0, nullptr, nullptr, 0,
          D_, 1, isd, -10.0f, 10.0f, 1);
      if (e < 3)   // ctx experts e+1..3 -> score cols [e*N, 3N)
        G(128, 0, dim3(16, QC_ / 128, 3 - e), xq, D_, 0, 0,
          xln_bf + (size_t)(e + 1) * ND, D_, ND, 0,
          scoresC + (size_t)e * N_, 3 * N_, N_, 0, nullptr, 0, 0, nullptr, nullptr, 0,
          D_, 1, isd, -10.0f, 10.0f, 1);
      softmax_rows<24><<<QC_, 256, 0, stream>>>(scoresC, 3 * N_, (u16*)scoresC, 2L * 3 * N_);
      // PV: z over ctx experts, atomic accumulate onto residual in x1
      if (e > 0)
        G(128, 0, dim3(4, QC_ / 128, e), (const u16*)scoresC, 2 * 3 * N_, N_, 0,
          xlnT_bf, N_, DN, 0,
          x1 + (size_t)q0 * D_, D_, 0, 0, nullptr, 0, 0, nullptr, nullptr, 0,
          N_, 1, 1.0f, 0, 0, 64);
      if (e < 3)
        G(128, 0, dim3(4, QC_ / 128, 3 - e), (const u16*)scoresC + (size_t)e * N_, 2 * 3 * N_, N_, 0,
          xlnT_bf + (size_t)(e + 1) * DN, N_, DN, 0,
          x1 + (size_t)q0 * D_, D_, 0, 0, nullptr, 0, 0, nullptr, nullptr, 0,
          N_, 1, 1.0f, 0, 0, 64);
    }
    cvt_f2bf<<<1024, 256, 0, stream>>>(x1, x1_bf, (size_t)N_ * D_);

    // ---- encoder layer ----
    G(128, 0, dim3(12, 16, 1), x1_bf, D_, 0, 0, ipw_e, D_, 0, 0,
      nullptr, 0, 0, 0, qkv_bf, 3 * D_, 0, ipb + (size_t)e * 3 * D_, nullptr, 0,
      D_, 1, 1.0f, 0, 0, 2);
    transpose_to_bf16<u16><<<dim3(16, 64, 1), 256, 0, stream>>>(
        qkv_bf + 2 * D_, 0, 3 * D_, vT_bf, 0, N_);
    hipMemsetAsync(sa32, 0, (size_t)N_ * D_ * 4, stream);
    for (int hp = 0; hp < 4; hp++) {
      const int h0 = hp * 2;
      // scores for 2 heads (z = head-in-pair)
      G(128, 0, dim3(16, 16, 2), qkv_bf + h0 * DH_, 3 * D_, DH_, 0,
        qkv_bf + D_ + h0 * DH_, 3 * D_, DH_, 0,
        sscores, N_, (long)N_ * N_, 0, nullptr, 0, 0, nullptr, nullptr, 0,
        DH_, 1, 0.125f, 0, 0, 0);
      softmax_rows<8><<<2 * N_, 256, 0, stream>>>(sscores, N_, (u16*)sscores, 2L * N_);
      // PV: z = (head-in-pair, K-split of 8), atomic into sa32
      G(64, 0, dim3(1, 16, 16), (const u16*)sscores, 2 * N_, (long)N_ * 2 * N_, 256,
        vT_bf + (size_t)h0 * DH_ * N_, N_, (long)DH_ * N_, 256,
        sa32 + h0 * DH_, D_, DH_, 0, nullptr, 0, 0, nullptr, nullptr, 0,
        256, 8, 1.0f, 0, 0, 64);
    }
    cvt_f2bf<<<1024, 256, 0, stream>>>(sa32, sa_bf, (size_t)N_ * D_);
    G(64, 0, dim3(8, 16, 1), sa_bf, D_, 0, 0, opw_e, D_, 0, 0,
      pre, D_, 0, 0, nullptr, 0, 0, opb + (size_t)e * D_, x1, D_,
      D_, 1, 1.0f, 0, 0, 2 | 8);
    ln_affine_kernel<<<N_, 256, 0, stream>>>(pre, n1w + (size_t)e * D_, n1b + (size_t)e * D_, x2f, x2_bf);
    G(128, 0, dim3(16, 16, 1), x2_bf, D_, 0, 0, w1_e, D_, 0, 0,
      nullptr, 0, 0, 0, ff1_bf, FF_, 0, b1 + (size_t)e * FF_, nullptr, 0,
      D_, 1, 1.0f, 0, 0, 2 | 4);
    G(64, 0, dim3(8, 16, 1), ff1_bf, FF_, 0, 0, w2_e, FF_, 0, 0,
      pre, D_, 0, 0, nullptr, 0, 0, b2 + (size_t)e * D_, x2f, D_,
      FF_, 1, 1.0f, 0, 0, 2 | 8);
    ln_affine_kernel<<<N_, 256, 0, stream>>>(pre, n2w + (size_t)e * D_, n2b + (size_t)e * D_, x3, x3_bf);
    transpose_to_bf16<u16><<<dim3(16, 64, 1), 256, 0, stream>>>(
        x3_bf, 0, D_, x3T_bf, 0, N_);

    // ---- hierarchical memory ----
    for (int l = 0; l < L_; l++) {
      G(128, 0, dim3(32, 16, 1), x3_bf, D_, 0, 0, mem_bf + (size_t)l * MM_ * D_, D_, 0, 0,
        ml, MM_, 0, 0, nullptr, 0, 0, nullptr, nullptr, 0,
        D_, 1, isd, -10.0f, 10.0f, 1);
      softmax_rows<16><<<N_, 256, 0, stream>>>(ml, MM_, (u16*)ml, 2L * MM_);
      // retr: am @ mem  (B = memT, both glds)
      G(64, 0, dim3(8, 16, 1), (const u16*)ml, 2 * MM_, 0, 0,
        memT_bf + (size_t)l * D_ * MM_, MM_, 0, 0,
        nullptr, 0, 0, 0, retr_bf + l * D_, L_ * D_, 0, nullptr, nullptr, 0,
        MM_, 1, 1.0f, 0, 0, 0);
      // upd: am^T @ x3  (A = am K-major via TA=1; B = x3T glds); clip then accum
      G(128, 1, dim3(4, 32, 1), (const u16*)ml, 2 * MM_, 0, 0, x3T_bf, N_, 0, 0,
        out_mem + (size_t)l * MM_ * D_, D_, 0, 0, nullptr, 0, 0, nullptr, nullptr, 0,
        N_, 1, 1.0f, -1.0f, 1.0f, 1 | 16);
    }
    G(64, 0, dim3(8, 16, 1), retr_bf, L_ * D_, 0, 0, agg_bf, L_ * D_, 0, 0,
      nullptr, 0, 0, 0, outs_bf + (size_t)e * N_ * D_, D_, 0, aggb, x3, D_,
      L_ * D_, 1, 1.0f, 0, 0, 2 | 8);
  }

  // ---- memory EMA + global fusion ----
  memfinal_kernel<<<(L_ * MM_ * D_ / 4 + 255) / 256, 256, 0, stream>>>(memories, out_mem);
  pooled_reduce_kernel<<<dim3(E_, D_ / 256, N_ / 256), 256, 0, stream>>>(outs_bf, pooled);
  gate_kernel<<<1, 256, 0, stream>>>(pooled, ggate, out_gate, gatew);
  fused_kernel<<<512, 256, 0, stream>>>(outs_bf, gatew, out_fused);
}

// Round 6
// 4742.043 us; speedup vs baseline: 1.4222x; 1.1899x over previous
//
#include <hip/hip_runtime.h>
#include <stdint.h>

#define E_ 4
#define N_ 2048
#define D_ 512
#define H_ 8
#define DH_ 64
#define FF_ 2048
#define L_ 4
#define MM_ 4096

typedef unsigned short u16;
typedef __attribute__((ext_vector_type(8))) short short8;
typedef __attribute__((ext_vector_type(8))) __bf16 bf16x8;
typedef __attribute__((ext_vector_type(4))) float f32x4;

__device__ __forceinline__ u16 f2bf(float f) {
  uint32_t u = __builtin_bit_cast(uint32_t, f);
  u = (u + 0x7fffu + ((u >> 16) & 1u)) >> 16;
  return (u16)u;
}
__device__ __forceinline__ float bf2f_(u16 h) {
  uint32_t u = ((uint32_t)h) << 16;
  return __builtin_bit_cast(float, u);
}
__device__ __forceinline__ float to_f(float x) { return x; }
__device__ __forceinline__ float to_f(u16 x) { return bf2f_(x); }

typedef __attribute__((address_space(3))) char lds_char;
typedef __attribute__((address_space(1))) const char glb_char;
__device__ __forceinline__ void glds16(const void* g, void* l) {
  __builtin_amdgcn_global_load_lds((glb_char*)g, (lds_char*)l, 16, 0, 0);
}

// ---------------------------------------------------------------------------
// gemm_big<BN>: C[M,N] = epi(alpha * A @ B^T). Tile 128 x BN, BK=32, NT, glds.
// flags: 1=CLIP 2=BIAS(col) 4=RELU 8=RESID f32 16=ACCUM(+C) 32=RESID bf16
//        64=ATOMIC-ADD into C (f32) 128=EXP (v = exp(v - esh))
// epilogue: v=alpha*acc -> clip -> exp -> *rscale[row] -> +bias -> relu ->
//           +resid -> atomic | (+Cold, store)
// z offsets: A/B += (z/zdiv)*s?z1 + (z%zdiv)*s?z2; C += zq*sCz1 + zr*sCz2;
//            Cb += z*sCbz; rscale += zq*sRSz.
// ---------------------------------------------------------------------------
template<int BN>
__global__ __launch_bounds__(256) void gemm_big(
    const u16* __restrict__ A, int lda, long sAz1, long sAz2,
    const u16* __restrict__ B, int ldb, long sBz1, long sBz2,
    float* __restrict__ C, int ldc, long sCz1, long sCz2,
    u16* __restrict__ Cb, int ldcb, long sCbz,
    const float* __restrict__ bias, const void* __restrict__ resid, int ldr,
    const float* __restrict__ rscale, long sRSz, float esh,
    int K, int zdiv, float alpha, float clo, float chi, int flags)
{
  __shared__ u16 As[128 * 32];
  __shared__ u16 Bs[BN * 32];
  const int z = blockIdx.z, zq = z / zdiv, zr = z % zdiv;
  A += (size_t)zq * sAz1 + (size_t)zr * sAz2;
  B += (size_t)zq * sBz1 + (size_t)zr * sBz2;
  const int m0 = blockIdx.y * 128, n0 = blockIdx.x * BN;
  const int t = threadIdx.x, lane = t & 63, w = t >> 6;
  constexpr int NI = (BN == 128) ? 4 : 2;
  const int WR = (BN == 128) ? ((w >> 1) * 64) : (w * 32);
  const int WC = (BN == 128) ? ((w & 1) * 64) : 0;
  const int fr = lane & 15, kg = lane >> 4;
  const int srw = lane >> 2, sck = (lane & 3) << 3;

  const u16* gA0 = A + (size_t)(m0 + w * 16 + srw) * lda + sck;
  const u16* gA1 = A + (size_t)(m0 + 64 + w * 16 + srw) * lda + sck;
  const u16* gB0 = B + (size_t)(n0 + w * 16 + srw) * ldb + sck;
  const u16* gB1 = nullptr;
  if constexpr (BN == 128) gB1 = B + (size_t)(n0 + 64 + w * 16 + srw) * ldb + sck;
  u16* lA0 = &As[(w * 16) * 32];
  u16* lA1 = &As[(64 + w * 16) * 32];
  u16* lB0 = &Bs[(w * 16) * 32];
  u16* lB1 = nullptr;
  if constexpr (BN == 128) lB1 = &Bs[(64 + w * 16) * 32];

  f32x4 acc[NI][4];
  #pragma unroll
  for (int i = 0; i < NI; i++)
    #pragma unroll
    for (int j = 0; j < 4; j++)
      #pragma unroll
      for (int r = 0; r < 4; r++) acc[i][j][r] = 0.0f;

  for (int k0 = 0; k0 < K; k0 += 32) {
    glds16(gA0, lA0); glds16(gA1, lA1); glds16(gB0, lB0);
    if constexpr (BN == 128) glds16(gB1, lB1);
    gA0 += 32; gA1 += 32; gB0 += 32;
    if constexpr (BN == 128) gB1 += 32;
    __syncthreads();
    bf16x8 af[NI], bfr[4];
    #pragma unroll
    for (int i = 0; i < NI; i++)
      af[i] = __builtin_bit_cast(bf16x8, *(const short8*)&As[(WR + i * 16 + fr) * 32 + kg * 8]);
    #pragma unroll
    for (int j = 0; j < 4; j++)
      bfr[j] = __builtin_bit_cast(bf16x8, *(const short8*)&Bs[(WC + j * 16 + fr) * 32 + kg * 8]);
    #pragma unroll
    for (int i = 0; i < NI; i++)
      #pragma unroll
      for (int j = 0; j < 4; j++)
        acc[i][j] = __builtin_amdgcn_mfma_f32_16x16x32_bf16(af[i], bfr[j], acc[i][j], 0, 0, 0);
    __syncthreads();
  }

  if (C)  C  += (size_t)zq * sCz1 + (size_t)zr * sCz2;
  if (Cb) Cb += (size_t)z * sCbz;
  if (rscale) rscale += (size_t)zq * sRSz;
  #pragma unroll
  for (int i = 0; i < NI; i++)
    #pragma unroll
    for (int j = 0; j < 4; j++) {
      const int row_b = m0 + WR + i * 16 + kg * 4;
      const int col = n0 + WC + j * 16 + fr;
      #pragma unroll
      for (int r = 0; r < 4; r++) {
        const int row = row_b + r;
        float v = alpha * acc[i][j][r];
        if (flags & 1)   v = fminf(fmaxf(v, clo), chi);
        if (flags & 128) v = __expf(v - esh);
        if (rscale)      v *= rscale[row];
        if (flags & 2)   v += bias[col];
        if (flags & 4)   v = fmaxf(v, 0.0f);
        if (flags & 8)   v += ((const float*)resid)[(size_t)row * ldr + col];
        if (flags & 32)  v += bf2f_(((const u16*)resid)[(size_t)row * ldr + col]);
        if (flags & 64)  { atomicAdd(&C[(size_t)row * ldc + col], v); continue; }
        if (flags & 16)  v += C[(size_t)row * ldc + col];
        if (C)  C[(size_t)row * ldc + col] = v;
        if (Cb) Cb[(size_t)row * ldcb + col] = f2bf(v);
      }
    }
}

// ---------------------------------------------------------------------------
// rowsum_inv<NV>: inv[row] = 1 / sum of NV*2048 bf16 values in row (ld u16)
// ---------------------------------------------------------------------------
template<int NV>
__global__ __launch_bounds__(256) void rowsum_inv(
    const u16* __restrict__ P, long ld, float* __restrict__ inv)
{
  const size_t row = blockIdx.x;
  const u16* p = P + row * ld;
  const int t = threadIdx.x;
  float s = 0.0f;
  #pragma unroll
  for (int i = 0; i < NV; i++) {
    short8 v = *(const short8*)&p[t * 8 + i * 2048];
    #pragma unroll
    for (int j = 0; j < 8; j++) s += bf2f_((u16)v[j]);
  }
  __shared__ float r[4];
  #pragma unroll
  for (int d = 32; d > 0; d >>= 1) s += __shfl_down(s, d);
  if ((t & 63) == 0) r[t >> 6] = s;
  __syncthreads();
  if (t == 0) inv[row] = 1.0f / (r[0] + r[1] + r[2] + r[3]);
}

// ---------------------------------------------------------------------------
__global__ __launch_bounds__(256) void ln_plain_kernel(
    const float* __restrict__ in, float* __restrict__ outf, u16* __restrict__ outb)
{
  const size_t row = blockIdx.x;
  const float* x = in + row * D_;
  const int t = threadIdx.x;
  float a = x[t], b = x[t + 256];
  float s = a + b, ss = a * a + b * b;
  __shared__ float r1[4], r2[4];
  #pragma unroll
  for (int d = 32; d > 0; d >>= 1) { s += __shfl_down(s, d); ss += __shfl_down(ss, d); }
  if ((t & 63) == 0) { r1[t >> 6] = s; r2[t >> 6] = ss; }
  __syncthreads();
  s = r1[0] + r1[1] + r1[2] + r1[3];
  ss = r2[0] + r2[1] + r2[2] + r2[3];
  const float mu = s * (1.0f / D_);
  const float inv = rsqrtf(ss * (1.0f / D_) - mu * mu + 1e-5f);
  const float y0 = (a - mu) * inv, y1 = (b - mu) * inv;
  if (outf) { outf[row * D_ + t] = y0;       outf[row * D_ + t + 256] = y1; }
  if (outb) { outb[row * D_ + t] = f2bf(y0); outb[row * D_ + t + 256] = f2bf(y1); }
}

__global__ __launch_bounds__(256) void ln_affine_kernel(
    const float* __restrict__ in, const float* __restrict__ w, const float* __restrict__ b,
    float* __restrict__ outf, u16* __restrict__ outb)
{
  const size_t row = blockIdx.x;
  const float* x = in + row * D_;
  const int t = threadIdx.x;
  float a = x[t], c = x[t + 256];
  float s = a + c, ss = a * a + c * c;
  __shared__ float r1[4], r2[4];
  #pragma unroll
  for (int d = 32; d > 0; d >>= 1) { s += __shfl_down(s, d); ss += __shfl_down(ss, d); }
  if ((t & 63) == 0) { r1[t >> 6] = s; r2[t >> 6] = ss; }
  __syncthreads();
  s = r1[0] + r1[1] + r1[2] + r1[3];
  ss = r2[0] + r2[1] + r2[2] + r2[3];
  const float mu = s * (1.0f / D_);
  const float inv = rsqrtf(ss * (1.0f / D_) - mu * mu + 1e-5f);
  const float y0 = (a - mu) * inv * w[t] + b[t];
  const float y1 = (c - mu) * inv * w[t + 256] + b[t + 256];
  if (outf) { outf[row * D_ + t] = y0;       outf[row * D_ + t + 256] = y1; }
  outb[row * D_ + t] = f2bf(y0); outb[row * D_ + t + 256] = f2bf(y1);
}

// ---------------------------------------------------------------------------
// Tiled transpose -> bf16: out[c][r] = bf16(in[r][c]); grid(cols/32, rows/32, z)
// ---------------------------------------------------------------------------
template<typename T>
__global__ __launch_bounds__(256) void transpose_to_bf16(
    const T* __restrict__ in, long in_batch, int ld_in,
    u16* __restrict__ out, long out_batch, int ld_out)
{
  __shared__ float tile[32][33];
  const int z = blockIdx.z;
  in  += (size_t)z * in_batch;
  out += (size_t)z * out_batch;
  const int c0 = blockIdx.x << 5, r0 = blockIdx.y << 5;
  const int tx = threadIdx.x & 31, ty = threadIdx.x >> 5;
  #pragma unroll
  for (int k = 0; k < 4; k++)
    tile[ty + 8 * k][tx] = to_f(in[(size_t)(r0 + ty + 8 * k) * ld_in + c0 + tx]);
  __syncthreads();
  #pragma unroll
  for (int k = 0; k < 4; k++)
    out[(size_t)(c0 + ty + 8 * k) * ld_out + r0 + tx] = f2bf(tile[tx][ty + 8 * k]);
}

// out[c][r] = bf16(in[r][c] * sc[r]); in f32 [rows][ld_in]
__global__ __launch_bounds__(256) void transpose_scale(
    const float* __restrict__ in, int ld_in, const float* __restrict__ sc,
    u16* __restrict__ out, int ld_out)
{
  __shared__ float tile[32][33];
  const int c0 = blockIdx.x << 5, r0 = blockIdx.y << 5;
  const int tx = threadIdx.x & 31, ty = threadIdx.x >> 5;
  #pragma unroll
  for (int k = 0; k < 4; k++) {
    const int r = r0 + ty + 8 * k;
    tile[ty + 8 * k][tx] = in[(size_t)r * ld_in + c0 + tx] * sc[r];
  }
  __syncthreads();
  #pragma unroll
  for (int k = 0; k < 4; k++)
    out[(size_t)(c0 + ty + 8 * k) * ld_out + r0 + tx] = f2bf(tile[tx][ty + 8 * k]);
}

__global__ __launch_bounds__(256) void cvt_f2bf(
    const float* __restrict__ in, u16* __restrict__ out, size_t n)
{
  size_t i = (size_t)blockIdx.x * 256 + threadIdx.x;
  const size_t stride = (size_t)gridDim.x * 256;
  for (; i < n; i += stride) out[i] = f2bf(in[i]);
}

// retr32 [2048][512] f32 -> out[r*ldo + c] bf16
__global__ __launch_bounds__(256) void cvt_rows512(
    const float* __restrict__ in, u16* __restrict__ out, int ldo)
{
  const size_t i4 = (size_t)blockIdx.x * 256 + threadIdx.x;
  const size_t base = i4 * 4;
  if (base >= (size_t)N_ * 512) return;
  const int r = (int)(base >> 9), c = (int)(base & 511);
  const f32x4 v = ((const f32x4*)in)[i4];
  u16* o = out + (size_t)r * ldo + c;
  o[0] = f2bf(v[0]); o[1] = f2bf(v[1]); o[2] = f2bf(v[2]); o[3] = f2bf(v[3]);
}

__global__ __launch_bounds__(256) void memfinal_kernel(
    const float* __restrict__ mem, float* __restrict__ io)
{
  const size_t i = (size_t)blockIdx.x * 256 + threadIdx.x;
  const size_t n4 = (size_t)L_ * MM_ * D_ / 4;
  if (i >= n4) return;
  const f32x4 m = ((const f32x4*)mem)[i];
  const f32x4 u = ((f32x4*)io)[i];
  f32x4 r;
  #pragma unroll
  for (int k = 0; k < 4; k++)
    r[k] = 0.9f * m[k] + fminf(fmaxf(0.1f * u[k], -0.1f), 0.1f);
  ((f32x4*)io)[i] = r;
}

__global__ __launch_bounds__(256) void pooled_reduce_kernel(
    const u16* __restrict__ outs, float* __restrict__ pooled)
{
  const int e = blockIdx.x, dc = blockIdx.y, nc = blockIdx.z;
  const int d = dc * 256 + threadIdx.x;
  const u16* p = outs + ((size_t)e * N_ + nc * 256) * D_ + d;
  float s = 0.0f;
  for (int i = 0; i < 256; i++) s += bf2f_(p[(size_t)i * D_]);
  atomicAdd(&pooled[e * D_ + d], s);
}

__global__ __launch_bounds__(256) void gate_kernel(
    const float* __restrict__ pooled, const float* __restrict__ gate,
    float* __restrict__ out_gw, float* __restrict__ ws_gw)
{
  const int t = threadIdx.x;
  const float g0 = gate[t], g1 = gate[t + 256];
  __shared__ float red[4][4];
  for (int e = 0; e < 4; e++) {
    float v = pooled[e * D_ + t] * g0 + pooled[e * D_ + t + 256] * g1;
    #pragma unroll
    for (int d = 32; d > 0; d >>= 1) v += __shfl_down(v, d);
    if ((t & 63) == 0) red[e][t >> 6] = v;
  }
  __syncthreads();
  if (t == 0) {
    float l[4], mx = -1e30f, sm = 0.0f;
    for (int e = 0; e < 4; e++) {
      l[e] = (red[e][0] + red[e][1] + red[e][2] + red[e][3]) * (1.0f / N_);
      l[e] = fminf(fmaxf(l[e], -10.0f), 10.0f);
      mx = fmaxf(mx, l[e]);
    }
    for (int e = 0; e < 4; e++) { l[e] = __expf(l[e] - mx); sm += l[e]; }
    for (int e = 0; e < 4; e++) { const float wv = l[e] / sm; out_gw[e] = wv; ws_gw[e] = wv; }
  }
}

__global__ __launch_bounds__(256) void fused_kernel(
    const u16* __restrict__ outs, const float* __restrict__ gw, float* __restrict__ out)
{
  const size_t i8 = ((size_t)blockIdx.x * 256 + threadIdx.x) * 8;
  const size_t s = (size_t)N_ * D_;
  if (i8 >= s) return;
  const float w0 = gw[0], w1 = gw[1], w2 = gw[2], w3 = gw[3];
  short8 v0 = *(const short8*)&outs[i8];
  short8 v1 = *(const short8*)&outs[i8 + s];
  short8 v2 = *(const short8*)&outs[i8 + 2 * s];
  short8 v3 = *(const short8*)&outs[i8 + 3 * s];
  float r[8];
  #pragma unroll
  for (int j = 0; j < 8; j++)
    r[j] = w0 * bf2f_((u16)v0[j]) + w1 * bf2f_((u16)v1[j]) +
           w2 * bf2f_((u16)v2[j]) + w3 * bf2f_((u16)v3[j]);
  *(f32x4*)&out[i8]     = *(f32x4*)&r[0];
  *(f32x4*)&out[i8 + 4] = *(f32x4*)&r[4];
}

// ---------------------------------------------------------------------------
extern "C" void kernel_launch(void* const* d_in, const int* in_sizes, int n_in,
                              void* d_out, int out_size, void* d_ws, size_t ws_size,
                              hipStream_t stream)
{
  (void)in_sizes; (void)n_in; (void)out_size; (void)ws_size;
  const float* tokens   = (const float*)d_in[0];
  const float* memories = (const float*)d_in[1];
  const float* ipw      = (const float*)d_in[2];
  const float* ipb      = (const float*)d_in[3];
  const float* opw      = (const float*)d_in[4];
  const float* opb      = (const float*)d_in[5];
  const float* w1       = (const float*)d_in[6];
  const float* b1       = (const float*)d_in[7];
  const float* w2       = (const float*)d_in[8];
  const float* b2       = (const float*)d_in[9];
  const float* n1w      = (const float*)d_in[10];
  const float* n1b      = (const float*)d_in[11];
  const float* n2w      = (const float*)d_in[12];
  const float* n2b      = (const float*)d_in[13];
  const float* aggw     = (const float*)d_in[14];
  const float* aggb     = (const float*)d_in[15];
  const float* ggate    = (const float*)d_in[16];

  float* out_fused = (float*)d_out;
  float* out_gate  = out_fused + (size_t)N_ * D_;
  float* out_mem   = out_gate + E_;          // [L][M][D], also the upd accumulator

  char* base = (char*)d_ws;
  size_t off = 0;
  auto alloc = [&](size_t b) -> char* {
    char* r = base + off; off += (b + 255) & ~(size_t)255; return r;
  };

  // persistent (~60.9 MB)
  u16* xln_bf  = (u16*)alloc((size_t)E_ * N_ * D_ * 2);
  u16* xlnT_bf = (u16*)alloc((size_t)E_ * D_ * N_ * 2);
  u16* mem_bf  = (u16*)alloc((size_t)L_ * MM_ * D_ * 2);
  u16* memT_bf = (u16*)alloc((size_t)L_ * D_ * MM_ * 2);
  u16* agg_bf  = (u16*)alloc((size_t)D_ * L_ * D_ * 2);
  u16* outs_bf = (u16*)alloc((size_t)E_ * N_ * D_ * 2);
  float* pooled = (float*)alloc((size_t)E_ * D_ * 4);
  float* gatew  = (float*)alloc(256);
  float* invA   = (float*)alloc(N_ * 4);        // cross rowsum
  float* invB   = (float*)alloc(2 * N_ * 4);    // self rowsum (2 heads)
  float* invC   = (float*)alloc(N_ * 4);        // memory rowsum
  // per-expert weights (~6.3 MB)
  u16* ipw_e = (u16*)alloc((size_t)3 * D_ * D_ * 2);
  u16* opw_e = (u16*)alloc((size_t)D_ * D_ * 2);
  u16* w1_e  = (u16*)alloc((size_t)FF_ * D_ * 2);
  u16* w2_e  = (u16*)alloc((size_t)D_ * FF_ * 2);
  // per-expert activations
  float* x1   = (float*)alloc((size_t)N_ * D_ * 4);    // residual; retr32 in memory phase
  float* retr32 = x1;
  u16* x1_bf  = (u16*)alloc((size_t)N_ * D_ * 2);
  u16* vT_bf  = (u16*)alloc((size_t)D_ * N_ * 2);      // self V^T
  u16* sa_bf  = (u16*)alloc((size_t)N_ * D_ * 2);      // x3sT in memory phase
  u16* x3sT   = sa_bf;
  u16* x2_bf  = (u16*)alloc((size_t)N_ * D_ * 2);
  u16* qkv_bf = (u16*)alloc((size_t)N_ * FF_ * 2);     // qkv | ff1 | retr_bf (disjoint)
  u16* ff1_bf = qkv_bf;
  u16* retr_bf= qkv_bf;
  float* x3   = (float*)alloc((size_t)N_ * D_ * 4);    // sa32 union
  float* sa32 = x3;
  u16* x3_bf  = (u16*)alloc((size_t)N_ * D_ * 2);
  // region RA 33.55MB (phase-disjoint):
  //  cross:  P_c bf16 [2048][6144] (25.2MB)
  //  self:   P2 bf16 [2][2048][2048] (16.8MB); then x2f@0 / pre@+8.4MB f32
  //  memory: P_bf bf16 [2048][4096] @0 (16.8MB) + amT bf16 [4096][2048] @+16.8MB
  char* RA = alloc((size_t)N_ * MM_ * 4);
  u16* P_c  = (u16*)RA;
  u16* P2   = (u16*)RA;
  u16* P_bf = (u16*)RA;
  u16* amT  = (u16*)(RA + (size_t)N_ * MM_ * 2);
  float* x2f = (float*)RA;
  float* pre = (float*)(RA + 8388608);

  auto G = [&](int BN, dim3 grid,
               const u16* A, int lda, long a1, long a2,
               const u16* B, int ldb, long b1, long b2,
               float* C, int ldc, long c1, long c2,
               u16* Cb, int ldcb, long cbz,
               const float* bias, const void* resid, int ldr,
               const float* rscale, long rsz, float esh,
               int K, int zdiv, float alpha, float clo, float chi, int flags) {
    if (BN == 128)
      gemm_big<128><<<grid, 256, 0, stream>>>(A, lda, a1, a2, B, ldb, b1, b2,
          C, ldc, c1, c2, Cb, ldcb, cbz, bias, resid, ldr, rscale, rsz, esh,
          K, zdiv, alpha, clo, chi, flags);
    else
      gemm_big<64><<<grid, 256, 0, stream>>>(A, lda, a1, a2, B, ldb, b1, b2,
          C, ldc, c1, c2, Cb, ldcb, cbz, bias, resid, ldr, rscale, rsz, esh,
          K, zdiv, alpha, clo, chi, flags);
  };

  const float isd = 0.04419417382415922f;  // 1/sqrt(512)
  const long ND = (long)N_ * D_;
  const long DN = (long)D_ * N_;

  hipMemsetAsync(out_mem, 0, (size_t)L_ * MM_ * D_ * 4, stream);
  hipMemsetAsync(pooled, 0, (size_t)E_ * D_ * 4, stream);

  // ---- setup ----
  ln_plain_kernel<<<E_ * N_, 256, 0, stream>>>(tokens, nullptr, xln_bf);
  transpose_to_bf16<u16><<<dim3(D_ / 32, N_ / 32, E_), 256, 0, stream>>>(
      xln_bf, ND, D_, xlnT_bf, DN, N_);
  cvt_f2bf<<<2048, 256, 0, stream>>>(memories, mem_bf, (size_t)L_ * MM_ * D_);
  transpose_to_bf16<float><<<dim3(D_ / 32, MM_ / 32, L_), 256, 0, stream>>>(
      memories, (long)MM_ * D_, D_, memT_bf, (long)D_ * MM_, MM_);
  cvt_f2bf<<<1024, 256, 0, stream>>>(aggw, agg_bf, (size_t)D_ * L_ * D_);

  for (int e = 0; e < E_; e++) {
    cvt_f2bf<<<768, 256, 0, stream>>>(ipw + (size_t)e * 3 * D_ * D_, ipw_e, (size_t)3 * D_ * D_);
    cvt_f2bf<<<256, 256, 0, stream>>>(opw + (size_t)e * D_ * D_, opw_e, (size_t)D_ * D_);
    cvt_f2bf<<<1024, 256, 0, stream>>>(w1 + (size_t)e * FF_ * D_, w1_e, (size_t)FF_ * D_);
    cvt_f2bf<<<1024, 256, 0, stream>>>(w2 + (size_t)e * D_ * FF_, w2_e, (size_t)D_ * FF_);
    ln_plain_kernel<<<N_, 256, 0, stream>>>(tokens + (size_t)e * N_ * D_, x1, nullptr);

    // ---- cross-expert attention (full 2048 rows, exp-epilogue) ----
    const u16* xq = xln_bf + (size_t)e * ND;
    if (e > 0)
      G(128, dim3(16, 16, e), xq, D_, 0, 0, xln_bf, D_, ND, 0,
        nullptr, 0, 0, 0, P_c, 3 * N_, N_, nullptr, nullptr, 0,
        nullptr, 0, 10.0f, D_, 1, isd, -10.0f, 10.0f, 1 | 128);
    if (e < 3)
      G(128, dim3(16, 16, 3 - e), xq, D_, 0, 0, xln_bf + (size_t)(e + 1) * ND, D_, ND, 0,
        nullptr, 0, 0, 0, P_c + e * N_, 3 * N_, N_, nullptr, nullptr, 0,
        nullptr, 0, 10.0f, D_, 1, isd, -10.0f, 10.0f, 1 | 128);
    rowsum_inv<3><<<N_, 256, 0, stream>>>(P_c, 3 * N_, invA);
    if (e > 0)
      G(128, dim3(4, 16, e), P_c, 3 * N_, N_, 0, xlnT_bf, N_, DN, 0,
        x1, D_, 0, 0, nullptr, 0, 0, nullptr, nullptr, 0,
        invA, 0, 0.0f, N_, 1, 1.0f, 0, 0, 64);
    if (e < 3)
      G(128, dim3(4, 16, 3 - e), P_c + e * N_, 3 * N_, N_, 0,
        xlnT_bf + (size_t)(e + 1) * DN, N_, DN, 0,
        x1, D_, 0, 0, nullptr, 0, 0, nullptr, nullptr, 0,
        invA, 0, 0.0f, N_, 1, 1.0f, 0, 0, 64);
    cvt_f2bf<<<1024, 256, 0, stream>>>(x1, x1_bf, (size_t)N_ * D_);

    // ---- encoder layer ----
    G(128, dim3(12, 16, 1), x1_bf, D_, 0, 0, ipw_e, D_, 0, 0,
      nullptr, 0, 0, 0, qkv_bf, 3 * D_, 0, ipb + (size_t)e * 3 * D_, nullptr, 0,
      nullptr, 0, 0.0f, D_, 1, 1.0f, 0, 0, 2);
    transpose_to_bf16<u16><<<dim3(16, 64, 1), 256, 0, stream>>>(
        qkv_bf + 2 * D_, 0, 3 * D_, vT_bf, 0, N_);
    hipMemsetAsync(sa32, 0, (size_t)N_ * D_ * 4, stream);
    for (int hp = 0; hp < 4; hp++) {
      const int h0 = hp * 2;
      // scores+exp for 2 heads -> P2 bf16
      G(128, dim3(16, 16, 2), qkv_bf + h0 * DH_, 3 * D_, DH_, 0,
        qkv_bf + D_ + h0 * DH_, 3 * D_, DH_, 0,
        nullptr, 0, 0, 0, P2, N_, (long)N_ * N_, nullptr, nullptr, 0,
        nullptr, 0, 0.0f, DH_, 1, 0.125f, 0, 0, 128);
      rowsum_inv<1><<<2 * N_, 256, 0, stream>>>(P2, N_, invB);
      // PV: z = (head-in-pair, ksplit 8), row-scaled atomics into sa32
      G(64, dim3(1, 16, 16), P2, N_, (long)N_ * N_, 256,
        vT_bf + (size_t)h0 * DH_ * N_, N_, (long)DH_ * N_, 256,
        sa32 + h0 * DH_, D_, DH_, 0, nullptr, 0, 0, nullptr, nullptr, 0,
        invB, N_, 0.0f, 256, 8, 1.0f, 0, 0, 64);
    }
    cvt_f2bf<<<1024, 256, 0, stream>>>(sa32, sa_bf, (size_t)N_ * D_);
    G(64, dim3(8, 16, 1), sa_bf, D_, 0, 0, opw_e, D_, 0, 0,
      pre, D_, 0, 0, nullptr, 0, 0, opb + (size_t)e * D_, x1, D_,
      nullptr, 0, 0.0f, D_, 1, 1.0f, 0, 0, 2 | 8);
    ln_affine_kernel<<<N_, 256, 0, stream>>>(pre, n1w + (size_t)e * D_, n1b + (size_t)e * D_, x2f, x2_bf);
    G(128, dim3(16, 16, 1), x2_bf, D_, 0, 0, w1_e, D_, 0, 0,
      nullptr, 0, 0, 0, ff1_bf, FF_, 0, b1 + (size_t)e * FF_, nullptr, 0,
      nullptr, 0, 0.0f, D_, 1, 1.0f, 0, 0, 2 | 4);
    G(64, dim3(8, 16, 1), ff1_bf, FF_, 0, 0, w2_e, FF_, 0, 0,
      pre, D_, 0, 0, nullptr, 0, 0, b2 + (size_t)e * D_, x2f, D_,
      nullptr, 0, 0.0f, FF_, 1, 1.0f, 0, 0, 2 | 8);
    ln_affine_kernel<<<N_, 256, 0, stream>>>(pre, n2w + (size_t)e * D_, n2b + (size_t)e * D_, x3, x3_bf);

    // ---- hierarchical memory ----
    for (int l = 0; l < L_; l++) {
      // logits+exp -> P_bf (compact bf16)
      G(128, dim3(32, 16, 1), x3_bf, D_, 0, 0, mem_bf + (size_t)l * MM_ * D_, D_, 0, 0,
        nullptr, 0, 0, 0, P_bf, MM_, 0, nullptr, nullptr, 0,
        nullptr, 0, 10.0f, D_, 1, isd, -10.0f, 10.0f, 1 | 128);
      rowsum_inv<2><<<N_, 256, 0, stream>>>(P_bf, MM_, invC);
      transpose_scale<<<dim3(16, 64, 1), 256, 0, stream>>>(x3, D_, invC, x3sT, N_);
      transpose_to_bf16<u16><<<dim3(128, 64, 1), 256, 0, stream>>>(
          P_bf, 0, MM_, amT, 0, N_);
      hipMemsetAsync(retr32, 0, (size_t)N_ * D_ * 4, stream);
      // retr: split-K x2, row-scaled atomics -> retr32
      G(64, dim3(8, 16, 2), P_bf, MM_, 0, 2048, memT_bf + (size_t)l * D_ * MM_, MM_, 0, 2048,
        retr32, D_, 0, 0, nullptr, 0, 0, nullptr, nullptr, 0,
        invC, 0, 0.0f, 2048, 2, 1.0f, 0, 0, 64);
      cvt_rows512<<<1024, 256, 0, stream>>>(retr32, retr_bf + l * D_, L_ * D_);
      // upd: amT @ x3sT^T, clip per expert, accumulate into out_mem
      G(64, dim3(8, 32, 1), amT, N_, 0, 0, x3sT, N_, 0, 0,
        out_mem + (size_t)l * MM_ * D_, D_, 0, 0, nullptr, 0, 0, nullptr, nullptr, 0,
        nullptr, 0, 0.0f, N_, 1, 1.0f, -1.0f, 1.0f, 1 | 16);
    }
    G(64, dim3(8, 16, 1), retr_bf, L_ * D_, 0, 0, agg_bf, L_ * D_, 0, 0,
      nullptr, 0, 0, 0, outs_bf + (size_t)e * N_ * D_, D_, 0, aggb, x3, D_,
      nullptr, 0, 0.0f, L_ * D_, 1, 1.0f, 0, 0, 2 | 8);
  }

  // ---- memory EMA + global fusion ----
  memfinal_kernel<<<(L_ * MM_ * D_ / 4 + 255) / 256, 256, 0, stream>>>(memories, out_mem);
  pooled_reduce_kernel<<<dim3(E_, D_ / 256, N_ / 256), 256, 0, stream>>>(outs_bf, pooled);
  gate_kernel<<<1, 256, 0, stream>>>(pooled, ggate, out_gate, gatew);
  fused_kernel<<<512, 256, 0, stream>>>(outs_bf, gatew, out_fused);
}